// Round 7
// baseline (315.782 us; speedup 1.0000x reference)
//
#include <hip/hip_runtime.h>
#include <hip/hip_bf16.h>
#include <hip/hip_fp16.h>

typedef float f32x4 __attribute__((ext_vector_type(4)));
typedef float f32x2 __attribute__((ext_vector_type(2)));
typedef __bf16 bf16x8 __attribute__((ext_vector_type(8)));
typedef short s16x8 __attribute__((ext_vector_type(8)));
typedef unsigned short u16;
typedef unsigned short ushort4v __attribute__((ext_vector_type(4)));

#define HWSZ 16384
#define NPIX 131072

// ws byte offsets (total ~43.1 MB)
#define XT_OFF    0u          // float[NPIX*64]  x transposed to NHWC
#define OFFS_OFF  33554432u   // float[NPIX*18]  offset-conv output, [pix][18]
#define WB_OFF    42991616u   // u16[64*576]     deform_w as bf16, [o][k2*64+c]
#define OFFR_OFF  43065344u   // float[576*18]   offset_w reordered [k2*64+c][18]
#define STATS_OFF 43106816u   // float[256]: (unused)[128], scale[64], shift[64]

#define VMWAIT(n) do { asm volatile("s_waitcnt vmcnt(" #n ")"); \
                       __builtin_amdgcn_sched_barrier(0); } while (0)

__device__ inline float dpp_add_x1(float v) {   // v + shfl_xor(v,1)
  int x = __builtin_amdgcn_update_dpp(0, __builtin_bit_cast(int, v), 0xB1, 0xF, 0xF, true);
  return v + __builtin_bit_cast(float, x);
}
__device__ inline float dpp_add_x2(float v) {   // v + shfl_xor(v,2)
  int x = __builtin_amdgcn_update_dpp(0, __builtin_bit_cast(int, v), 0x4E, 0xF, 0xF, true);
  return v + __builtin_bit_cast(float, x);
}

// ---- prep: reorder/convert weights ----
__global__ void kprep(const float* __restrict__ dw, const float* __restrict__ ow,
                      u16* __restrict__ Wb, float* __restrict__ offr) {
  int t = blockIdx.x * 256 + threadIdx.x;
  if (t < 36864) {                      // deform_w (64,64,3,3) -> Wb[o][k2*64+c] bf16
    int o = t / 576, r = t % 576;
    int c = r / 9, k2 = r % 9;
    __hip_bfloat16 h = __float2bfloat16(dw[t]);
    Wb[o * 576 + k2 * 64 + c] = __builtin_bit_cast(u16, h);
  } else if (t < 47232) {               // offset_w (18,64,3,3) -> offr[k2*64+c][18]
    int t2 = t - 36864;
    int oc = t2 / 576, r = t2 % 576;
    int c = r / 9, k2 = r % 9;
    offr[(k2 * 64 + c) * 18 + oc] = ow[t2];
  }
}

// ---- NCHW -> NHWC transpose of x (feeds kdeform gathers) ----
__global__ void ktrans(const float* __restrict__ x, float* __restrict__ xt) {
  __shared__ float tile[64][65];
  int blk = blockIdx.x;
  int b = blk >> 8, hwT = (blk & 255) * 64;
  int tx = threadIdx.x & 63, ty = threadIdx.x >> 6;
  const float* xp = x + (size_t)b * 64 * HWSZ;
#pragma unroll
  for (int r = 0; r < 16; ++r) {
    int c = r * 4 + ty;
    tile[c][tx] = xp[c * HWSZ + hwT + tx];
  }
  __syncthreads();
  float* xo = xt + ((size_t)b * HWSZ + hwT) * 64;
#pragma unroll
  for (int r = 0; r < 16; ++r) {
    int hwl = r * 4 + ty;
    xo[hwl * 64 + tx] = tile[tx][hwl];
  }
}

// ---- offset conv: 3x3, 64->18 ch, fp32, thread per pixel, NCHW x (coalesced) ----
__global__ void koffc(const float* __restrict__ x, const float* __restrict__ offr,
                      const float* __restrict__ offb, float* __restrict__ offs) {
  int pix = blockIdx.x * 256 + threadIdx.x;
  int b = pix >> 14, hw = pix & 16383;
  int h = hw >> 7, w = hw & 127;
  float acc[18];
#pragma unroll
  for (int oc = 0; oc < 18; ++oc) acc[oc] = offb[oc];
  const float* xb = x + (size_t)b * 64 * HWSZ;
#pragma unroll
  for (int k2 = 0; k2 < 9; ++k2) {
    int yy = h - 1 + k2 / 3, xx = w - 1 + k2 % 3;
    if ((unsigned)yy < 128u && (unsigned)xx < 128u) {
      const float* px = xb + yy * 128 + xx;       // lane-consecutive (coalesced)
      const float* wr = offr + k2 * 64 * 18;      // wave-uniform (scalarized)
#pragma unroll 4
      for (int c = 0; c < 64; ++c) {
        float xv = px[(size_t)c * HWSZ];
#pragma unroll
        for (int oc = 0; oc < 18; ++oc)
          acc[oc] = fmaf(wr[c * 18 + oc], xv, acc[oc]);
      }
    }
  }
  float* op = offs + (size_t)pix * 18;
#pragma unroll
  for (int oc = 0; oc < 18; ++oc) op[oc] = acc[oc];
}

// ---- deformable conv: 2-deep counted-vmcnt pipelined gathers + DPP reduce + MFMA ----
// block: 256 thr = 4 waves; tile = 64 o x 32 pixels; K = 576 (k2*64+c)
// LDS: S 36864 + OFF 2304 = 39168 B -> 4 blocks/CU
__global__ __launch_bounds__(256, 4) void kdeform(
    const float* __restrict__ xt, const float* __restrict__ offs,
    const u16* __restrict__ Wb, const float* __restrict__ db,
    float* __restrict__ y) {
  __shared__ u16 S[32 * 576];          // XOR-swizzled: u16idx ^= (row&7)<<3
  __shared__ float OFF[576];           // this block's 32 pixels x 18 offsets
  int tid = threadIdx.x;
  int lane = tid & 63, wid = tid >> 6;
  int bid = blockIdx.x;
  int batch = bid & 7, tile = bid >> 3;
  int base = (batch << 14) + tile * 32;
  int b = batch;

  // stage this block's offsets into LDS (coalesced, once)
  if (tid < 144)
    ((f32x4*)OFF)[tid] = *(const f32x4*)(offs + (size_t)base * 18 + tid * 4);
  __syncthreads();

  // sampling lane decomposition: corner = lane&3 (00,01,10,11 = y0x0,y0x1,y1x0,y1x1)
  int corner = lane & 3, c4 = lane >> 2;
  int gxsel = lane & 1, gysel = (lane >> 1) & 1;
  int lanebyte = c4 << 4;
  int shamt = gxsel << 4;              // 0 or 16: which half of packed weight

  // meta lanes: lane t<9 computes tap t
  int t = lane;
  int ky = t / 3, kx = t % 3;
  int tt = (t < 9) ? t : 0;
  int p0 = wid * 8;

  auto meta = [&](int pix, f32x2 dc, int& MO, int& WA, int& WB2) {
    int hw = pix & 16383;
    int h = hw >> 7, w = hw & 127;
    float sy = (float)(h - 1 + ky) + dc.x;
    float sx = (float)(w - 1 + kx) + dc.y;
    float fy = floorf(sy), fx = floorf(sx);
    int y0 = (int)fy, x0 = (int)fx;
    float wy1 = sy - fy, wx1 = sx - fx;
    float ay0 = ((unsigned)y0 < 128u) ? 1.f - wy1 : 0.f;
    float ay1 = ((unsigned)(y0 + 1) < 128u) ? wy1 : 0.f;
    float ax0 = ((unsigned)x0 < 128u) ? 1.f - wx1 : 0.f;
    float ax1 = ((unsigned)(x0 + 1) < 128u) ? wx1 : 0.f;
    int y0c = min(max(y0, 0), 127), x0c = min(max(x0, 0), 127);
    int dys = min(max(y0 + 1, 0), 127) - y0c;
    int dxs = min(max(x0 + 1, 0), 127) - x0c;
    MO = ((b << 14) + y0c * 128 + x0c) | (dxs << 24) | (dys << 25);
    WA = __builtin_bit_cast(int, __floats2half2_rn(ay0 * ax0, ay0 * ax1));
    WB2 = __builtin_bit_cast(int, __floats2half2_rn(ay1 * ax0, ay1 * ax1));
  };

  // issue pixel i's 9 gathers (asm volatile: order pinned vs the counted waits)
  auto issue_px = [&](int i, f32x4 (&vv)[9], int (&wAo)[9], int (&wBo)[9]) {
    int p = p0 + i;
    int pix = base + p;
    f32x2 dc = *(const f32x2*)&OFF[p * 18 + 2 * tt];
    int MO, WA, WB2;
    meta(pix, dc, MO, WA, WB2);
#pragma unroll
    for (int k = 0; k < 9; ++k) {
      int mk = __builtin_amdgcn_readlane(MO, k);
      wAo[k] = __builtin_amdgcn_readlane(WA, k);
      wBo[k] = __builtin_amdgcn_readlane(WB2, k);
      int sdx = (mk >> 24) & 1;
      int sdy = ((mk >> 25) & 1) << 7;
      int po = (mk & 0xFFFFFF) + (gxsel ? sdx : 0) + (gysel ? sdy : 0);
      const char* ap = (const char*)xt + ((size_t)(unsigned)po << 8) + lanebyte;
      asm volatile("global_load_dwordx4 %0, %1, off" : "=v"(vv[k]) : "v"(ap));
    }
  };

  // weighted cross-corner reduce (DPP within quads), group-leader writes LDS
  auto reduce_px = [&](int i, const f32x4 (&vv)[9], const int (&wAo)[9],
                       const int (&wBo)[9]) {
    int p = p0 + i;
#pragma unroll
    for (int k = 0; k < 9; ++k) {
      int hsel = gysel ? wBo[k] : wAo[k];
      __half hh = __builtin_bit_cast(__half, (u16)(hsel >> shamt));
      float w = __half2float(hh);
      float r0 = vv[k][0] * w, r1 = vv[k][1] * w, r2 = vv[k][2] * w, r3 = vv[k][3] * w;
      r0 = dpp_add_x2(dpp_add_x1(r0));
      r1 = dpp_add_x2(dpp_add_x1(r1));
      r2 = dpp_add_x2(dpp_add_x1(r2));
      r3 = dpp_add_x2(dpp_add_x1(r3));
      if (corner == 0) {
        ushort4v pk;
        pk.x = __builtin_bit_cast(u16, __float2bfloat16(r0));
        pk.y = __builtin_bit_cast(u16, __float2bfloat16(r1));
        pk.z = __builtin_bit_cast(u16, __float2bfloat16(r2));
        pk.w = __builtin_bit_cast(u16, __float2bfloat16(r3));
        int idx = (p * 576 + k * 64 + (c4 << 2)) ^ ((p & 7) << 3);
        *(ushort4v*)&S[idx] = pk;
      }
    }
  };

  // ---- 2-deep software pipeline: wait vmcnt(9) steady, drain only at tail ----
  f32x4 vA[9], vB[9];
  int wA0[9], wB0[9], wA1[9], wB1[9];
  issue_px(0, vA, wA0, wB0);
  issue_px(1, vB, wA1, wB1);
  VMWAIT(9); reduce_px(0, vA, wA0, wB0); issue_px(2, vA, wA0, wB0);
  VMWAIT(9); reduce_px(1, vB, wA1, wB1); issue_px(3, vB, wA1, wB1);
  VMWAIT(9); reduce_px(2, vA, wA0, wB0); issue_px(4, vA, wA0, wB0);
  VMWAIT(9); reduce_px(3, vB, wA1, wB1); issue_px(5, vB, wA1, wB1);
  VMWAIT(9); reduce_px(4, vA, wA0, wB0); issue_px(6, vA, wA0, wB0);
  VMWAIT(9); reduce_px(5, vB, wA1, wB1); issue_px(7, vB, wA1, wB1);
  VMWAIT(9); reduce_px(6, vA, wA0, wB0);
  VMWAIT(0); reduce_px(7, vB, wA1, wB1);

  // A fragments via asm loads (after sampling buffers are dead)
  s16x8 afr[18];
  const u16* wrow = Wb + (wid * 16 + (lane & 15)) * 576 + (lane >> 4) * 8;
#pragma unroll
  for (int kc = 0; kc < 18; ++kc)
    asm volatile("global_load_dwordx4 %0, %1, off" : "=v"(afr[kc]) : "v"(wrow + kc * 32));

  __syncthreads();
  asm volatile("s_waitcnt vmcnt(0)");
  __builtin_amdgcn_sched_barrier(0);

  f32x4 zero = {0.f, 0.f, 0.f, 0.f};
  f32x4 acc[2] = {zero, zero};
#pragma unroll
  for (int kc = 0; kc < 18; ++kc) {
#pragma unroll
    for (int nf = 0; nf < 2; ++nf) {
      int row = nf * 16 + (lane & 15);
      int idx = (row * 576 + kc * 32 + (lane >> 4) * 8) ^ ((row & 7) << 3);
      bf16x8 bfr = __builtin_bit_cast(bf16x8, *(const s16x8*)&S[idx]);
      acc[nf] = __builtin_amdgcn_mfma_f32_16x16x32_bf16(
          __builtin_bit_cast(bf16x8, afr[kc]), bfr, acc[nf], 0, 0, 0);
    }
  }

  // epilogue: write y (NCHW) only — stats computed by kstats pass
  int obase = wid * 16 + (lane >> 4) * 4;
#pragma unroll
  for (int nf = 0; nf < 2; ++nf) {
    int pix = base + nf * 16 + (lane & 15);
    int hw = pix & 16383;
    float* yp = y + (size_t)b * (64 * HWSZ) + hw;
#pragma unroll
    for (int r = 0; r < 4; ++r) {
      int o = obase + r;
      yp[(size_t)o * HWSZ] = acc[nf][r] + db[o];
    }
  }
}

// ---- BN stats: one block per channel, no atomics ----
__global__ void kstats(const float* __restrict__ y, const float* __restrict__ gamma,
                       const float* __restrict__ beta, float* __restrict__ stats) {
  __shared__ float r1[256], r2[256];
  int o = blockIdx.x;
  int tid = threadIdx.x;
  float s1 = 0.f, s2 = 0.f;
  for (int b = 0; b < 8; ++b) {
    const float* yp = y + (size_t)b * (64 * HWSZ) + (size_t)o * HWSZ;
    for (int i = tid * 4; i < HWSZ; i += 1024) {
      f32x4 v = *(const f32x4*)(yp + i);
#pragma unroll
      for (int j = 0; j < 4; ++j) { s1 += v[j]; s2 += v[j] * v[j]; }
    }
  }
  r1[tid] = s1; r2[tid] = s2;
  __syncthreads();
  for (int s = 128; s > 0; s >>= 1) {
    if (tid < s) { r1[tid] += r1[tid + s]; r2[tid] += r2[tid + s]; }
    __syncthreads();
  }
  if (tid == 0) {
    float m = r1[0] * (1.f / 131072.f);
    float v = r2[0] * (1.f / 131072.f) - m * m;
    float sc = gamma[o] * rsqrtf(v + 1e-5f);
    stats[128 + o] = sc;
    stats[192 + o] = beta[o] - m * sc;
  }
}

// ---- in-place scale/shift + PReLU on y (= d_out) ----
__global__ void kfinal(float* __restrict__ y, const float* __restrict__ stats,
                       const float* __restrict__ pa) {
  float a = pa[0];
  int total = NPIX * 64 / 4;
  for (int i = blockIdx.x * blockDim.x + threadIdx.x; i < total;
       i += gridDim.x * blockDim.x) {
    int o = (i >> 12) & 63;
    f32x4 v = ((const f32x4*)y)[i];
    float sc = stats[128 + o], sh = stats[192 + o];
#pragma unroll
    for (int j = 0; j < 4; ++j) {
      float t = fmaf(v[j], sc, sh);
      v[j] = t >= 0.f ? t : a * t;
    }
    ((f32x4*)y)[i] = v;
  }
}

extern "C" void kernel_launch(void* const* d_in, const int* in_sizes, int n_in,
                              void* d_out, int out_size, void* d_ws, size_t ws_size,
                              hipStream_t stream) {
  const float* x  = (const float*)d_in[0];
  const float* ow = (const float*)d_in[1];
  const float* ob = (const float*)d_in[2];
  const float* dw = (const float*)d_in[3];
  const float* db = (const float*)d_in[4];
  const float* gm = (const float*)d_in[5];
  const float* bt = (const float*)d_in[6];
  const float* pa = (const float*)d_in[7];
  char* ws = (char*)d_ws;
  float* xt    = (float*)(ws + XT_OFF);
  float* offs  = (float*)(ws + OFFS_OFF);
  u16*   Wb    = (u16*)(ws + WB_OFF);
  float* offr  = (float*)(ws + OFFR_OFF);
  float* stats = (float*)(ws + STATS_OFF);
  float* y = (float*)d_out;   // d_out doubles as the pre-BN activation buffer

  kprep<<<185, 256, 0, stream>>>(dw, ow, Wb, offr);
  ktrans<<<2048, 256, 0, stream>>>(x, xt);
  koffc<<<512, 256, 0, stream>>>(x, offr, ob, offs);
  kdeform<<<4096, 256, 0, stream>>>(xt, offs, Wb, db, y);
  kstats<<<64, 256, 0, stream>>>(y, gm, bt, stats);
  kfinal<<<2048, 256, 0, stream>>>(y, stats, pa);
}

// Round 10
// 224.585 us; speedup vs baseline: 1.4061x; 1.4061x over previous
//
#include <hip/hip_runtime.h>
#include <hip/hip_bf16.h>
#include <hip/hip_fp16.h>

typedef float f32x4 __attribute__((ext_vector_type(4)));
typedef float f32x2 __attribute__((ext_vector_type(2)));
typedef unsigned int u32;
typedef u32 u32x4 __attribute__((ext_vector_type(4)));
typedef __bf16 bf16x8 __attribute__((ext_vector_type(8)));
typedef short s16x8 __attribute__((ext_vector_type(8)));
typedef unsigned short u16;

#define HWSZ 16384
#define NPIX 131072

// ws byte offsets (round-7 layout: xt is f32)
#define XT_OFF    0u          // float[NPIX*64]  x transposed to NHWC
#define OFFS_OFF  33554432u   // float[NPIX*18]  offset-conv output, [pix][18]
#define WB_OFF    42991616u   // u16(bf16)[64*576]  deform_w, [o][k2*64+c]
#define OFFR_OFF  43065344u   // float[576*18]   offset_w reordered [k2*64+c][18]
#define STATS_OFF 43106816u   // float[256]: (unused)[128], scale[64], shift[64]

__device__ inline u32 pkbf(float lo, float hi) {
  u16 l = __builtin_bit_cast(u16, __float2bfloat16(lo));
  u16 h = __builtin_bit_cast(u16, __float2bfloat16(hi));
  return (u32)l | ((u32)h << 16);
}

// ---- prep: reorder/convert weights to bf16 (round-7 version) ----
__global__ void kprep(const float* __restrict__ dw, const float* __restrict__ ow,
                      u16* __restrict__ Wb, float* __restrict__ offr) {
  int t = blockIdx.x * 256 + threadIdx.x;
  if (t < 36864) {                      // deform_w (64,64,3,3) -> Wb[o][k2*64+c] bf16
    int o = t / 576, r = t % 576;
    int c = r / 9, k2 = r % 9;
    __hip_bfloat16 h = __float2bfloat16(dw[t]);
    Wb[o * 576 + k2 * 64 + c] = __builtin_bit_cast(u16, h);
  } else if (t < 47232) {               // offset_w (18,64,3,3) -> offr[k2*64+c][18]
    int t2 = t - 36864;
    int oc = t2 / 576, r = t2 % 576;
    int c = r / 9, k2 = r % 9;
    offr[(k2 * 64 + c) * 18 + oc] = ow[t2];
  }
}

// ---- NCHW -> NHWC f32 transpose of x (round-7 version) ----
__global__ void ktrans(const float* __restrict__ x, float* __restrict__ xt) {
  __shared__ float tile[64][65];
  int blk = blockIdx.x;
  int b = blk >> 8, hwT = (blk & 255) * 64;
  int tx = threadIdx.x & 63, ty = threadIdx.x >> 6;
  const float* xp = x + (size_t)b * 64 * HWSZ;
#pragma unroll
  for (int r = 0; r < 16; ++r) {
    int c = r * 4 + ty;
    tile[c][tx] = xp[c * HWSZ + hwT + tx];
  }
  __syncthreads();
  float* xo = xt + ((size_t)b * HWSZ + hwT) * 64;
#pragma unroll
  for (int r = 0; r < 16; ++r) {
    int hwl = r * 4 + ty;
    xo[hwl * 64 + tx] = tile[tx][hwl];
  }
}

// ---- offset conv: 3x3, 64->18 ch, fp32, thread per pixel, NCHW x (coalesced) ----
__global__ void koffc(const float* __restrict__ x, const float* __restrict__ offr,
                      const float* __restrict__ offb, float* __restrict__ offs) {
  int pix = blockIdx.x * 256 + threadIdx.x;
  int b = pix >> 14, hw = pix & 16383;
  int h = hw >> 7, w = hw & 127;
  float acc[18];
#pragma unroll
  for (int oc = 0; oc < 18; ++oc) acc[oc] = offb[oc];
  const float* xb = x + (size_t)b * 64 * HWSZ;
#pragma unroll
  for (int k2 = 0; k2 < 9; ++k2) {
    int yy = h - 1 + k2 / 3, xx = w - 1 + k2 % 3;
    if ((unsigned)yy < 128u && (unsigned)xx < 128u) {
      const float* px = xb + yy * 128 + xx;       // lane-consecutive (coalesced)
      const float* wr = offr + k2 * 64 * 18;      // wave-uniform (scalarized)
#pragma unroll 4
      for (int c = 0; c < 64; ++c) {
        float xv = px[(size_t)c * HWSZ];
#pragma unroll
        for (int oc = 0; oc < 18; ++oc)
          acc[oc] = fmaf(wr[c * 18 + oc], xv, acc[oc]);
      }
    }
  }
  float* op = offs + (size_t)pix * 18;
#pragma unroll
  for (int oc = 0; oc < 18; ++oc) op[oc] = acc[oc];
}

// ---- deformable conv: LDS meta + (pixel,octet) in-lane f32 interp + bf16 MFMA ----
// block: 256 thr = 4 waves; tile = 64 o x 32 pixels; K = 576 (k2*64+c)
// lane = (pixel 0..7)*8 + (ch-octet 0..7); 4 corners in-lane, f32 interp
// LDS: S 36864 + mW 4608 + mPos 1152 + mStep 1152 + OFF 2304 = 46080 B -> 3 blocks/CU
__global__ __launch_bounds__(256, 3) void kdeform(
    const float* __restrict__ xt, const float* __restrict__ offs,
    const u16* __restrict__ Wb, const float* __restrict__ db,
    float* __restrict__ y) {
  __shared__ u16 S[32 * 576];          // bf16, XOR-swizzled: u16idx ^= (row&7)<<3
  __shared__ f32x4 mW[288];            // per (pix,tap): {w00,w01,w10,w11}
  __shared__ u32 mPos[288];            // byte offset of corner00 pixel in xt
  __shared__ u32 mStep[288];           // dxB(256) | dyB(32768)
  __shared__ float OFF[576];           // this block's 32 pixels x 18 offsets
  int tid = threadIdx.x;
  int lane = tid & 63, wid = tid >> 6;
  int bid = blockIdx.x;
  int batch = bid & 7, tilei = bid >> 3;
  int base = (batch << 14) + tilei * 32;
  int b = batch;

  // stage this block's offsets into LDS (coalesced, once)
  if (tid < 144)
    ((f32x4*)OFF)[tid] = *(const f32x4*)(offs + (size_t)base * 18 + tid * 4);
  __syncthreads();

  // ---- phase 0: per-(pixel,tap) meta, cooperative (288 tasks), all f32 ----
  for (int t = tid; t < 288; t += 256) {
    int tp = t / 9, k2 = t - tp * 9;
    int pix = base + tp;
    int hw = pix & 16383;
    int h = hw >> 7, w = hw & 127;
    float dy = OFF[tp * 18 + 2 * k2], dx = OFF[tp * 18 + 2 * k2 + 1];
    float sy = (float)(h - 1 + k2 / 3) + dy;
    float sx = (float)(w - 1 + k2 % 3) + dx;
    float fy = floorf(sy), fx = floorf(sx);
    int y0 = (int)fy, x0 = (int)fx;
    float wy1 = sy - fy, wx1 = sx - fx;
    float ay0 = ((unsigned)y0 < 128u) ? 1.f - wy1 : 0.f;
    float ay1 = ((unsigned)(y0 + 1) < 128u) ? wy1 : 0.f;
    float ax0 = ((unsigned)x0 < 128u) ? 1.f - wx1 : 0.f;
    float ax1 = ((unsigned)(x0 + 1) < 128u) ? wx1 : 0.f;
    int y0c = min(max(y0, 0), 127), x0c = min(max(x0, 0), 127);
    int dys = min(max(y0 + 1, 0), 127) - y0c;
    int dxs = min(max(x0 + 1, 0), 127) - x0c;
    f32x4 wv = {ay0 * ax0, ay0 * ax1, ay1 * ax0, ay1 * ax1};
    mW[t] = wv;
    mPos[t] = (u32)(((b << 14) + y0c * 128 + x0c) * 256);
    mStep[t] = (dxs ? 256u : 0u) | (dys ? 32768u : 0u);
  }
  __syncthreads();

  // ---- phase 1: sampling — lane = (pix 0..7)*8 + oct; f32 interp, unrolled ----
  int oct32 = (lane & 7) << 5;         // byte offset of octet within pixel's 256B
  int oct8 = (lane & 7) << 3;          // u16 offset of octet within pixel's 64ch
  int p = wid * 8 + (lane >> 3);       // this lane's pixel (0..31)
  const char* xb = (const char*)xt;

#pragma unroll
  for (int k = 0; k < 9; ++k) {
    int t = p * 9 + k;
    f32x4 w = mW[t];                   // ds_read_b128 (8-lane broadcast)
    u32 pos = mPos[t], st = mStep[t];
    u32 dxB = st & 256u, dyB = st & 32768u;
    const char* pb = xb + pos + oct32;
    f32x4 a00 = *(const f32x4*)pb;
    f32x4 b00 = *(const f32x4*)(pb + 16);
    f32x4 a01 = *(const f32x4*)(pb + dxB);
    f32x4 b01 = *(const f32x4*)(pb + dxB + 16);
    f32x4 a10 = *(const f32x4*)(pb + dyB);
    f32x4 b10 = *(const f32x4*)(pb + dyB + 16);
    f32x4 a11 = *(const f32x4*)(pb + dyB + dxB);
    f32x4 b11 = *(const f32x4*)(pb + dyB + dxB + 16);
    f32x4 sA, sB;
#pragma unroll
    for (int j = 0; j < 4; ++j) {
      sA[j] = fmaf(w.w, a11[j], fmaf(w.z, a10[j], fmaf(w.y, a01[j], w.x * a00[j])));
      sB[j] = fmaf(w.w, b11[j], fmaf(w.z, b10[j], fmaf(w.y, b01[j], w.x * b00[j])));
    }
    u32x4 out;
    out[0] = pkbf(sA[0], sA[1]);
    out[1] = pkbf(sA[2], sA[3]);
    out[2] = pkbf(sB[0], sB[1]);
    out[3] = pkbf(sB[2], sB[3]);
    int idx = (p * 576 + k * 64 + oct8) ^ ((p & 7) << 3);
    *(u32x4*)&S[idx] = out;            // ds_write_b128 (16B aligned, swizzled)
  }

  // A fragments (bf16 weights), plain vector loads
  s16x8 afr[18];
  const u16* wrow = Wb + (wid * 16 + (lane & 15)) * 576 + (lane >> 4) * 8;
#pragma unroll
  for (int kc = 0; kc < 18; ++kc)
    afr[kc] = *(const s16x8*)(wrow + kc * 32);

  __syncthreads();

  f32x4 zero = {0.f, 0.f, 0.f, 0.f};
  f32x4 acc[2] = {zero, zero};
#pragma unroll
  for (int kc = 0; kc < 18; ++kc) {
#pragma unroll
    for (int nf = 0; nf < 2; ++nf) {
      int row = nf * 16 + (lane & 15);
      int idx = (row * 576 + kc * 32 + (lane >> 4) * 8) ^ ((row & 7) << 3);
      bf16x8 bfr = __builtin_bit_cast(bf16x8, *(const s16x8*)&S[idx]);
      acc[nf] = __builtin_amdgcn_mfma_f32_16x16x32_bf16(
          __builtin_bit_cast(bf16x8, afr[kc]), bfr, acc[nf], 0, 0, 0);
    }
  }

  // epilogue: write y (NCHW) only — stats computed by kstats pass
  int obase = wid * 16 + (lane >> 4) * 4;
#pragma unroll
  for (int nf = 0; nf < 2; ++nf) {
    int pix = base + nf * 16 + (lane & 15);
    int hw = pix & 16383;
    float* yp = y + (size_t)b * (64 * HWSZ) + hw;
#pragma unroll
    for (int r = 0; r < 4; ++r) {
      int o = obase + r;
      yp[(size_t)o * HWSZ] = acc[nf][r] + db[o];
    }
  }
}

// ---- BN stats: one block per channel, no atomics ----
__global__ void kstats(const float* __restrict__ y, const float* __restrict__ gamma,
                       const float* __restrict__ beta, float* __restrict__ stats) {
  __shared__ float r1[256], r2[256];
  int o = blockIdx.x;
  int tid = threadIdx.x;
  float s1 = 0.f, s2 = 0.f;
  for (int b = 0; b < 8; ++b) {
    const float* yp = y + (size_t)b * (64 * HWSZ) + (size_t)o * HWSZ;
    for (int i = tid * 4; i < HWSZ; i += 1024) {
      f32x4 v = *(const f32x4*)(yp + i);
#pragma unroll
      for (int j = 0; j < 4; ++j) { s1 += v[j]; s2 += v[j] * v[j]; }
    }
  }
  r1[tid] = s1; r2[tid] = s2;
  __syncthreads();
  for (int s = 128; s > 0; s >>= 1) {
    if (tid < s) { r1[tid] += r1[tid + s]; r2[tid] += r2[tid + s]; }
    __syncthreads();
  }
  if (tid == 0) {
    float m = r1[0] * (1.f / 131072.f);
    float v = r2[0] * (1.f / 131072.f) - m * m;
    float sc = gamma[o] * rsqrtf(v + 1e-5f);
    stats[128 + o] = sc;
    stats[192 + o] = beta[o] - m * sc;
  }
}

// ---- in-place scale/shift + PReLU on y (= d_out) ----
__global__ void kfinal(float* __restrict__ y, const float* __restrict__ stats,
                       const float* __restrict__ pa) {
  float a = pa[0];
  int total = NPIX * 64 / 4;
  for (int i = blockIdx.x * blockDim.x + threadIdx.x; i < total;
       i += gridDim.x * blockDim.x) {
    int o = (i >> 12) & 63;
    f32x4 v = ((const f32x4*)y)[i];
    float sc = stats[128 + o], sh = stats[192 + o];
#pragma unroll
    for (int j = 0; j < 4; ++j) {
      float t = fmaf(v[j], sc, sh);
      v[j] = t >= 0.f ? t : a * t;
    }
    ((f32x4*)y)[i] = v;
  }
}

extern "C" void kernel_launch(void* const* d_in, const int* in_sizes, int n_in,
                              void* d_out, int out_size, void* d_ws, size_t ws_size,
                              hipStream_t stream) {
  const float* x  = (const float*)d_in[0];
  const float* ow = (const float*)d_in[1];
  const float* ob = (const float*)d_in[2];
  const float* dw = (const float*)d_in[3];
  const float* db = (const float*)d_in[4];
  const float* gm = (const float*)d_in[5];
  const float* bt = (const float*)d_in[6];
  const float* pa = (const float*)d_in[7];
  char* ws = (char*)d_ws;
  float* xt    = (float*)(ws + XT_OFF);
  float* offs  = (float*)(ws + OFFS_OFF);
  u16*   Wb    = (u16*)(ws + WB_OFF);
  float* offr  = (float*)(ws + OFFR_OFF);
  float* stats = (float*)(ws + STATS_OFF);
  float* y = (float*)d_out;   // d_out doubles as the pre-BN activation buffer

  kprep<<<185, 256, 0, stream>>>(dw, ow, Wb, offr);
  ktrans<<<2048, 256, 0, stream>>>(x, xt);
  koffc<<<512, 256, 0, stream>>>(x, offr, ob, offs);
  kdeform<<<4096, 256, 0, stream>>>(xt, offs, Wb, db, y);
  kstats<<<64, 256, 0, stream>>>(y, gm, bt, stats);
  kfinal<<<2048, 256, 0, stream>>>(y, stats, pa);
}

// Round 11
// 160.699 us; speedup vs baseline: 1.9650x; 1.3975x over previous
//
#include <hip/hip_runtime.h>
#include <hip/hip_bf16.h>
#include <hip/hip_fp16.h>

typedef float f32x4 __attribute__((ext_vector_type(4)));
typedef unsigned int u32;
typedef u32 u32x4 __attribute__((ext_vector_type(4)));
typedef __bf16 bf16x8 __attribute__((ext_vector_type(8)));
typedef short s16x8 __attribute__((ext_vector_type(8)));
typedef unsigned short u16;

#define HWSZ 16384
#define NPIX 131072

// ws byte offsets
#define XT_OFF    0u          // float[NPIX*64]  x transposed to NHWC
#define OFFS_OFF  33554432u   // float[NPIX*18]  offset-conv output, [pix][18]
#define WB_OFF    42991616u   // u16(bf16)[64*576]  deform_w, [o][k2*64+c]
#define OFFR_OFF  43065344u   // float[576*18]   (legacy, unused)
#define STATS_OFF 43106816u   // float[256]: (unused)[128], scale[64], shift[64]
#define WO_OFF    43107840u   // u16(bf16)[32*576]  offset_w padded, [oc][k2*64+c]
#define PART_OFF  43144704u   // float[1024]: part1[512], part2[512]

__device__ inline u32 pkbf(float lo, float hi) {
  u16 l = __builtin_bit_cast(u16, __float2bfloat16(lo));
  u16 h = __builtin_bit_cast(u16, __float2bfloat16(hi));
  return (u32)l | ((u32)h << 16);
}

// ---- prep: reorder/convert weights to bf16 ----
__global__ void kprep(const float* __restrict__ dw, const float* __restrict__ ow,
                      u16* __restrict__ Wb, u16* __restrict__ Wo) {
  int t = blockIdx.x * 256 + threadIdx.x;
  if (t < 36864) {                      // deform_w (64,64,3,3) -> Wb[o][k2*64+c] bf16
    int o = t / 576, r = t % 576;
    int c = r / 9, k2 = r % 9;
    __hip_bfloat16 h = __float2bfloat16(dw[t]);
    Wb[o * 576 + k2 * 64 + c] = __builtin_bit_cast(u16, h);
  } else if (t < 55296) {               // offset_w (18,64,3,3) -> Wo[oc][k2*64+c], pad to 32
    int t2 = t - 36864;                 // t2 in [0, 18432)
    int oc = t2 / 576, r = t2 % 576;
    int c = r / 9, k2 = r % 9;
    float v = (oc < 18) ? ow[(oc * 64 + c) * 9 + k2] : 0.f;
    __hip_bfloat16 h = __float2bfloat16(v);
    Wo[oc * 576 + k2 * 64 + c] = __builtin_bit_cast(u16, h);
  }
}

// ---- NCHW -> NHWC f32 transpose of x ----
__global__ void ktrans(const float* __restrict__ x, float* __restrict__ xt) {
  __shared__ float tile[64][65];
  int blk = blockIdx.x;
  int b = blk >> 8, hwT = (blk & 255) * 64;
  int tx = threadIdx.x & 63, ty = threadIdx.x >> 6;
  const float* xp = x + (size_t)b * 64 * HWSZ;
#pragma unroll
  for (int r = 0; r < 16; ++r) {
    int c = r * 4 + ty;
    tile[c][tx] = xp[c * HWSZ + hwT + tx];
  }
  __syncthreads();
  float* xo = xt + ((size_t)b * HWSZ + hwT) * 64;
#pragma unroll
  for (int r = 0; r < 16; ++r) {
    int hwl = r * 4 + ty;
    xo[hwl * 64 + tx] = tile[tx][hwl];
  }
}

// ---- offset conv as MFMA GEMM: offs[18 x NPIX] = Wo[18x576] . im2col ----
// block: 256 thr = 4 waves; tile = 32 output-ch-rows (18 valid) x 32 pixels
// wave quadrant: mr = wid>>1 (oc half), nr = wid&1 (pixel half); 18 MFMA/wave
// LDS: S 36864 B -> 4 blocks/CU
__global__ __launch_bounds__(256, 4) void koffg(
    const float* __restrict__ xt, const u16* __restrict__ Wo,
    const float* __restrict__ offb, float* __restrict__ offs) {
  __shared__ u16 S[32 * 576];          // bf16, XOR-swizzled: u16idx ^= (row&7)<<3
  int tid = threadIdx.x;
  int lane = tid & 63, wid = tid >> 6;
  int bid = blockIdx.x;
  int batch = bid & 7, tilei = bid >> 3;
  int base = (batch << 14) + tilei * 32;
  int b = batch;
  int hw0 = base & 16383;
  int h = hw0 >> 7, w0 = hw0 & 127;    // all 32 pixels share row h; px = w0..w0+31

  // ---- S-build: lane = (pix 0..7)*8 + oct; 9 shifted reads, f32->bf16 ----
  int oct = lane & 7;
  int p = wid * 8 + (lane >> 3);       // this lane's pixel (0..31)
  int px = w0 + p;
  const char* xb = (const char*)xt;
#pragma unroll
  for (int k2 = 0; k2 < 9; ++k2) {
    int ky = k2 / 3, kx = k2 % 3;
    int yy = h - 1 + ky, xx = px - 1 + kx;
    u32x4 out = {0u, 0u, 0u, 0u};
    if ((unsigned)yy < 128u && (unsigned)xx < 128u) {
      const char* pb = xb + (size_t)(((b << 14) + yy * 128 + xx) * 256) + (oct << 5);
      f32x4 a = *(const f32x4*)pb;
      f32x4 c = *(const f32x4*)(pb + 16);
      out[0] = pkbf(a[0], a[1]);
      out[1] = pkbf(a[2], a[3]);
      out[2] = pkbf(c[0], c[1]);
      out[3] = pkbf(c[2], c[3]);
    }
    int idx = (p * 576 + k2 * 64 + oct * 8) ^ ((p & 7) << 3);
    *(u32x4*)&S[idx] = out;            // ds_write_b128
  }

  // A fragments: Wo rows for this wave's 16 oc rows
  int mr = wid >> 1, nr = wid & 1;
  s16x8 afr[18];
  const u16* wrow = Wo + (mr * 16 + (lane & 15)) * 576 + (lane >> 4) * 8;
#pragma unroll
  for (int kc = 0; kc < 18; ++kc)
    afr[kc] = *(const s16x8*)(wrow + kc * 32);

  __syncthreads();

  f32x4 acc = {0.f, 0.f, 0.f, 0.f};
#pragma unroll
  for (int kc = 0; kc < 18; ++kc) {
    int row = nr * 16 + (lane & 15);
    int idx = (row * 576 + kc * 32 + (lane >> 4) * 8) ^ ((row & 7) << 3);
    bf16x8 bfr = __builtin_bit_cast(bf16x8, *(const s16x8*)&S[idx]);
    acc = __builtin_amdgcn_mfma_f32_16x16x32_bf16(
        __builtin_bit_cast(bf16x8, afr[kc]), bfr, acc, 0, 0, 0);
  }

  // epilogue: offs[pix][oc] = acc + bias for oc < 18
  int pix = base + nr * 16 + (lane & 15);
  int ocb = mr * 16 + (lane >> 4) * 4;
#pragma unroll
  for (int r = 0; r < 4; ++r) {
    int oc = ocb + r;
    if (oc < 18) offs[(size_t)pix * 18 + oc] = acc[r] + offb[oc];
  }
}

// ---- deformable conv: LDS meta + (pixel,octet) in-lane f32 interp + bf16 MFMA ----
// (structure identical to passing round 10)
__global__ __launch_bounds__(256, 3) void kdeform(
    const float* __restrict__ xt, const float* __restrict__ offs,
    const u16* __restrict__ Wb, const float* __restrict__ db,
    float* __restrict__ y) {
  __shared__ u16 S[32 * 576];          // bf16, XOR-swizzled: u16idx ^= (row&7)<<3
  __shared__ f32x4 mW[288];            // per (pix,tap): {w00,w01,w10,w11}
  __shared__ u32 mPos[288];            // byte offset of corner00 pixel in xt
  __shared__ u32 mStep[288];           // dxB(256) | dyB(32768)
  __shared__ float OFF[576];           // this block's 32 pixels x 18 offsets
  int tid = threadIdx.x;
  int lane = tid & 63, wid = tid >> 6;
  int bid = blockIdx.x;
  int batch = bid & 7, tilei = bid >> 3;
  int base = (batch << 14) + tilei * 32;
  int b = batch;

  if (tid < 144)
    ((f32x4*)OFF)[tid] = *(const f32x4*)(offs + (size_t)base * 18 + tid * 4);
  __syncthreads();

  // ---- phase 0: per-(pixel,tap) meta, cooperative (288 tasks), all f32 ----
  for (int t = tid; t < 288; t += 256) {
    int tp = t / 9, k2 = t - tp * 9;
    int pix = base + tp;
    int hw = pix & 16383;
    int h = hw >> 7, w = hw & 127;
    float dy = OFF[tp * 18 + 2 * k2], dx = OFF[tp * 18 + 2 * k2 + 1];
    float sy = (float)(h - 1 + k2 / 3) + dy;
    float sx = (float)(w - 1 + k2 % 3) + dx;
    float fy = floorf(sy), fx = floorf(sx);
    int y0 = (int)fy, x0 = (int)fx;
    float wy1 = sy - fy, wx1 = sx - fx;
    float ay0 = ((unsigned)y0 < 128u) ? 1.f - wy1 : 0.f;
    float ay1 = ((unsigned)(y0 + 1) < 128u) ? wy1 : 0.f;
    float ax0 = ((unsigned)x0 < 128u) ? 1.f - wx1 : 0.f;
    float ax1 = ((unsigned)(x0 + 1) < 128u) ? wx1 : 0.f;
    int y0c = min(max(y0, 0), 127), x0c = min(max(x0, 0), 127);
    int dys = min(max(y0 + 1, 0), 127) - y0c;
    int dxs = min(max(x0 + 1, 0), 127) - x0c;
    f32x4 wv = {ay0 * ax0, ay0 * ax1, ay1 * ax0, ay1 * ax1};
    mW[t] = wv;
    mPos[t] = (u32)(((b << 14) + y0c * 128 + x0c) * 256);
    mStep[t] = (dxs ? 256u : 0u) | (dys ? 32768u : 0u);
  }
  __syncthreads();

  // ---- phase 1: sampling — lane = (pix 0..7)*8 + oct; f32 interp, unrolled ----
  int oct32 = (lane & 7) << 5;
  int oct8 = (lane & 7) << 3;
  int p = wid * 8 + (lane >> 3);
  const char* xb = (const char*)xt;

#pragma unroll
  for (int k = 0; k < 9; ++k) {
    int t = p * 9 + k;
    f32x4 w = mW[t];
    u32 pos = mPos[t], st = mStep[t];
    u32 dxB = st & 256u, dyB = st & 32768u;
    const char* pb = xb + pos + oct32;
    f32x4 a00 = *(const f32x4*)pb;
    f32x4 b00 = *(const f32x4*)(pb + 16);
    f32x4 a01 = *(const f32x4*)(pb + dxB);
    f32x4 b01 = *(const f32x4*)(pb + dxB + 16);
    f32x4 a10 = *(const f32x4*)(pb + dyB);
    f32x4 b10 = *(const f32x4*)(pb + dyB + 16);
    f32x4 a11 = *(const f32x4*)(pb + dyB + dxB);
    f32x4 b11 = *(const f32x4*)(pb + dyB + dxB + 16);
    f32x4 sA, sB;
#pragma unroll
    for (int j = 0; j < 4; ++j) {
      sA[j] = fmaf(w.w, a11[j], fmaf(w.z, a10[j], fmaf(w.y, a01[j], w.x * a00[j])));
      sB[j] = fmaf(w.w, b11[j], fmaf(w.z, b10[j], fmaf(w.y, b01[j], w.x * b00[j])));
    }
    u32x4 out;
    out[0] = pkbf(sA[0], sA[1]);
    out[1] = pkbf(sA[2], sA[3]);
    out[2] = pkbf(sB[0], sB[1]);
    out[3] = pkbf(sB[2], sB[3]);
    int idx = (p * 576 + k * 64 + oct8) ^ ((p & 7) << 3);
    *(u32x4*)&S[idx] = out;
  }

  s16x8 afr[18];
  const u16* wrow = Wb + (wid * 16 + (lane & 15)) * 576 + (lane >> 4) * 8;
#pragma unroll
  for (int kc = 0; kc < 18; ++kc)
    afr[kc] = *(const s16x8*)(wrow + kc * 32);

  __syncthreads();

  f32x4 zero = {0.f, 0.f, 0.f, 0.f};
  f32x4 acc[2] = {zero, zero};
#pragma unroll
  for (int kc = 0; kc < 18; ++kc) {
#pragma unroll
    for (int nf = 0; nf < 2; ++nf) {
      int row = nf * 16 + (lane & 15);
      int idx = (row * 576 + kc * 32 + (lane >> 4) * 8) ^ ((row & 7) << 3);
      bf16x8 bfr = __builtin_bit_cast(bf16x8, *(const s16x8*)&S[idx]);
      acc[nf] = __builtin_amdgcn_mfma_f32_16x16x32_bf16(
          __builtin_bit_cast(bf16x8, afr[kc]), bfr, acc[nf], 0, 0, 0);
    }
  }

  int obase = wid * 16 + (lane >> 4) * 4;
#pragma unroll
  for (int nf = 0; nf < 2; ++nf) {
    int pix = base + nf * 16 + (lane & 15);
    int hw = pix & 16383;
    float* yp = y + (size_t)b * (64 * HWSZ) + hw;
#pragma unroll
    for (int r = 0; r < 4; ++r) {
      int o = obase + r;
      yp[(size_t)o * HWSZ] = acc[nf][r] + db[o];
    }
  }
}

// ---- BN stats pass 1: one block per (batch, channel) plane, no atomics ----
__global__ void kstats(const float* __restrict__ y, float* __restrict__ part) {
  __shared__ float r1[256], r2[256];
  int bo = blockIdx.x;                  // b*64 + o
  int tid = threadIdx.x;
  const float* yp = y + (size_t)bo * HWSZ;
  float s1 = 0.f, s2 = 0.f;
  for (int i = tid * 4; i < HWSZ; i += 1024) {
    f32x4 v = *(const f32x4*)(yp + i);
#pragma unroll
    for (int j = 0; j < 4; ++j) { s1 += v[j]; s2 += v[j] * v[j]; }
  }
  r1[tid] = s1; r2[tid] = s2;
  __syncthreads();
  for (int s = 128; s > 0; s >>= 1) {
    if (tid < s) { r1[tid] += r1[tid + s]; r2[tid] += r2[tid + s]; }
    __syncthreads();
  }
  if (tid == 0) { part[bo] = r1[0]; part[512 + bo] = r2[0]; }
}

// ---- BN finalize ----
__global__ void kbnf(const float* __restrict__ part, const float* __restrict__ gamma,
                     const float* __restrict__ beta, float* __restrict__ stats) {
  int o = threadIdx.x;
  if (o < 64) {
    float s1 = 0.f, s2 = 0.f;
#pragma unroll
    for (int b = 0; b < 8; ++b) {
      s1 += part[b * 64 + o];
      s2 += part[512 + b * 64 + o];
    }
    float m = s1 * (1.f / 131072.f);
    float v = s2 * (1.f / 131072.f) - m * m;
    float sc = gamma[o] * rsqrtf(v + 1e-5f);
    stats[128 + o] = sc;
    stats[192 + o] = beta[o] - m * sc;
  }
}

// ---- in-place scale/shift + PReLU on y (= d_out) ----
__global__ void kfinal(float* __restrict__ y, const float* __restrict__ stats,
                       const float* __restrict__ pa) {
  float a = pa[0];
  int total = NPIX * 64 / 4;
  for (int i = blockIdx.x * blockDim.x + threadIdx.x; i < total;
       i += gridDim.x * blockDim.x) {
    int o = (i >> 12) & 63;
    f32x4 v = ((const f32x4*)y)[i];
    float sc = stats[128 + o], sh = stats[192 + o];
#pragma unroll
    for (int j = 0; j < 4; ++j) {
      float t = fmaf(v[j], sc, sh);
      v[j] = t >= 0.f ? t : a * t;
    }
    ((f32x4*)y)[i] = v;
  }
}

extern "C" void kernel_launch(void* const* d_in, const int* in_sizes, int n_in,
                              void* d_out, int out_size, void* d_ws, size_t ws_size,
                              hipStream_t stream) {
  const float* x  = (const float*)d_in[0];
  const float* ow = (const float*)d_in[1];
  const float* ob = (const float*)d_in[2];
  const float* dw = (const float*)d_in[3];
  const float* db = (const float*)d_in[4];
  const float* gm = (const float*)d_in[5];
  const float* bt = (const float*)d_in[6];
  const float* pa = (const float*)d_in[7];
  char* ws = (char*)d_ws;
  float* xt    = (float*)(ws + XT_OFF);
  float* offs  = (float*)(ws + OFFS_OFF);
  u16*   Wb    = (u16*)(ws + WB_OFF);
  u16*   Wo    = (u16*)(ws + WO_OFF);
  float* stats = (float*)(ws + STATS_OFF);
  float* part  = (float*)(ws + PART_OFF);
  float* y = (float*)d_out;   // d_out doubles as the pre-BN activation buffer

  kprep<<<216, 256, 0, stream>>>(dw, ow, Wb, Wo);
  ktrans<<<2048, 256, 0, stream>>>(x, xt);
  koffg<<<4096, 256, 0, stream>>>(xt, Wo, ob, offs);
  kdeform<<<4096, 256, 0, stream>>>(xt, offs, Wb, db, y);
  kstats<<<512, 256, 0, stream>>>(y, part);
  kbnf<<<1, 64, 0, stream>>>(part, gm, bt, stats);
  kfinal<<<2048, 256, 0, stream>>>(y, stats, pa);
}

// Round 12
// 140.250 us; speedup vs baseline: 2.2516x; 1.1458x over previous
//
#include <hip/hip_runtime.h>
#include <hip/hip_bf16.h>
#include <hip/hip_fp16.h>

typedef float f32x4 __attribute__((ext_vector_type(4)));
typedef float f32x2 __attribute__((ext_vector_type(2)));
typedef unsigned int u32;
typedef u32 u32x4 __attribute__((ext_vector_type(4)));
typedef __bf16 bf16x8 __attribute__((ext_vector_type(8)));
typedef short s16x8 __attribute__((ext_vector_type(8)));
typedef unsigned short u16;

#define HWSZ 16384
#define NPIX 131072

// ws byte offsets
#define XT_OFF    0u          // u16(bf16)[NPIX*64]  x transposed to NHWC (16.78 MB)
#define OFFS_OFF  33554432u   // float[NPIX*18]  offset-conv output, [pix][18]
#define WB_OFF    42991616u   // u16(bf16)[64*576]  deform_w, [o][k2*64+c]
#define STATS_OFF 43106816u   // float[256]: (unused)[128], scale[64], shift[64]
#define WO_OFF    43107840u   // u16(bf16)[32*576]  offset_w padded, [oc][k2*64+c]
#define PART_OFF  43144704u   // float[1024]: part1[512], part2[512]

__device__ inline u32 pkbf(float lo, float hi) {
  u16 l = __builtin_bit_cast(u16, __float2bfloat16(lo));
  u16 h = __builtin_bit_cast(u16, __float2bfloat16(hi));
  return (u32)l | ((u32)h << 16);
}
__device__ inline float bflo(u32 u) { return __builtin_bit_cast(float, u << 16); }
__device__ inline float bfhi(u32 u) { return __builtin_bit_cast(float, u & 0xFFFF0000u); }

// ---- prep: reorder/convert weights to bf16 ----
__global__ void kprep(const float* __restrict__ dw, const float* __restrict__ ow,
                      u16* __restrict__ Wb, u16* __restrict__ Wo) {
  int t = blockIdx.x * 256 + threadIdx.x;
  if (t < 36864) {                      // deform_w (64,64,3,3) -> Wb[o][k2*64+c] bf16
    int o = t / 576, r = t % 576;
    int c = r / 9, k2 = r % 9;
    __hip_bfloat16 h = __float2bfloat16(dw[t]);
    Wb[o * 576 + k2 * 64 + c] = __builtin_bit_cast(u16, h);
  } else if (t < 55296) {               // offset_w (18,64,3,3) -> Wo[oc][k2*64+c], pad to 32
    int t2 = t - 36864;
    int oc = t2 / 576, r = t2 % 576;
    int c = r / 9, k2 = r % 9;
    float v = (oc < 18) ? ow[(oc * 64 + c) * 9 + k2] : 0.f;
    __hip_bfloat16 h = __float2bfloat16(v);
    Wo[oc * 576 + k2 * 64 + c] = __builtin_bit_cast(u16, h);
  }
}

// ---- NCHW f32 -> NHWC bf16 transpose of x ----
__global__ void ktrans(const float* __restrict__ x, u16* __restrict__ xt) {
  __shared__ float tile[64][65];
  int blk = blockIdx.x;
  int b = blk >> 8, hwT = (blk & 255) * 64;
  int tx = threadIdx.x & 63, ty = threadIdx.x >> 6;
  const float* xp = x + (size_t)b * 64 * HWSZ;
#pragma unroll
  for (int r = 0; r < 16; ++r) {
    int c = r * 4 + ty;
    tile[c][tx] = xp[c * HWSZ + hwT + tx];
  }
  __syncthreads();
  u16* xo = xt + ((size_t)b * HWSZ + hwT) * 64;
#pragma unroll
  for (int r = 0; r < 16; ++r) {
    int hwl = r * 4 + ty;
    __hip_bfloat16 h = __float2bfloat16(tile[tx][hwl]);
    xo[hwl * 64 + tx] = __builtin_bit_cast(u16, h);
  }
}

// ---- offset conv as MFMA GEMM: offs[18 x NPIX] = Wo[18x576] . im2col ----
// S-build is now a straight bf16 copy from xt (no conversion).
__global__ __launch_bounds__(256, 4) void koffg(
    const u16* __restrict__ xt, const u16* __restrict__ Wo,
    const float* __restrict__ offb, float* __restrict__ offs) {
  __shared__ u16 S[32 * 576];          // bf16, XOR-swizzled: u16idx ^= (row&7)<<3
  int tid = threadIdx.x;
  int lane = tid & 63, wid = tid >> 6;
  int bid = blockIdx.x;
  int batch = bid & 7, tilei = bid >> 3;
  int base = (batch << 14) + tilei * 32;
  int b = batch;
  int hw0 = base & 16383;
  int h = hw0 >> 7, w0 = hw0 & 127;    // all 32 pixels share row h

  int oct = lane & 7;
  int p = wid * 8 + (lane >> 3);
  int px = w0 + p;
  const char* xb = (const char*)xt;
#pragma unroll
  for (int k2 = 0; k2 < 9; ++k2) {
    int ky = k2 / 3, kx = k2 % 3;
    int yy = h - 1 + ky, xx = px - 1 + kx;
    u32x4 out = {0u, 0u, 0u, 0u};
    if ((unsigned)yy < 128u && (unsigned)xx < 128u) {
      const char* pb = xb + (size_t)(((b << 14) + yy * 128 + xx) * 128) + (oct << 4);
      out = *(const u32x4*)pb;
    }
    int idx = (p * 576 + k2 * 64 + oct * 8) ^ ((p & 7) << 3);
    *(u32x4*)&S[idx] = out;
  }

  int mr = wid >> 1, nr = wid & 1;
  s16x8 afr[18];
  const u16* wrow = Wo + (mr * 16 + (lane & 15)) * 576 + (lane >> 4) * 8;
#pragma unroll
  for (int kc = 0; kc < 18; ++kc)
    afr[kc] = *(const s16x8*)(wrow + kc * 32);

  __syncthreads();

  f32x4 acc = {0.f, 0.f, 0.f, 0.f};
#pragma unroll
  for (int kc = 0; kc < 18; ++kc) {
    int row = nr * 16 + (lane & 15);
    int idx = (row * 576 + kc * 32 + (lane >> 4) * 8) ^ ((row & 7) << 3);
    bf16x8 bfr = __builtin_bit_cast(bf16x8, *(const s16x8*)&S[idx]);
    acc = __builtin_amdgcn_mfma_f32_16x16x32_bf16(
        __builtin_bit_cast(bf16x8, afr[kc]), bfr, acc, 0, 0, 0);
  }

  int pix = base + nr * 16 + (lane & 15);
  int ocb = mr * 16 + (lane >> 4) * 4;
#pragma unroll
  for (int r = 0; r < 4; ++r) {
    int oc = ocb + r;
    if (oc < 18) offs[(size_t)pix * 18 + oc] = acc[r] + offb[oc];
  }
}

// ---- deformable conv: slim meta (f16-pair weights) + bf16 gathers + bf16 MFMA ----
// LDS: S 36864 + mWp 2304 + mPos 1152 = 40320 B -> 4 blocks/CU
__global__ __launch_bounds__(256, 4) void kdeform(
    const u16* __restrict__ xt, const float* __restrict__ offs,
    const u16* __restrict__ Wb, const float* __restrict__ db,
    float* __restrict__ y) {
  __shared__ u16 S[32 * 576];          // bf16, XOR-swizzled: u16idx ^= (row&7)<<3
  __shared__ u32 mWp[288 * 2];         // per (pix,tap): f16x2 {w00,w01},{w10,w11}
  __shared__ u32 mPos[288];            // pixel_byte(×128) | dxs | dys<<1
  int tid = threadIdx.x;
  int lane = tid & 63, wid = tid >> 6;
  int bid = blockIdx.x;
  int batch = bid & 7, tilei = bid >> 3;
  int base = (batch << 14) + tilei * 32;
  int b = batch;

  // ---- phase 0: per-(pixel,tap) meta (288 tasks); offs read direct (L2) ----
  for (int t = tid; t < 288; t += 256) {
    int tp = t / 9, k2 = t - tp * 9;
    int pix = base + tp;
    int hw = pix & 16383;
    int h = hw >> 7, w = hw & 127;
    f32x2 d = *(const f32x2*)(offs + (size_t)pix * 18 + 2 * k2);
    float sy = (float)(h - 1 + k2 / 3) + d.x;
    float sx = (float)(w - 1 + k2 % 3) + d.y;
    float fy = floorf(sy), fx = floorf(sx);
    int y0 = (int)fy, x0 = (int)fx;
    float wy1 = sy - fy, wx1 = sx - fx;
    float ay0 = ((unsigned)y0 < 128u) ? 1.f - wy1 : 0.f;
    float ay1 = ((unsigned)(y0 + 1) < 128u) ? wy1 : 0.f;
    float ax0 = ((unsigned)x0 < 128u) ? 1.f - wx1 : 0.f;
    float ax1 = ((unsigned)(x0 + 1) < 128u) ? wx1 : 0.f;
    int y0c = min(max(y0, 0), 127), x0c = min(max(x0, 0), 127);
    int dys = min(max(y0 + 1, 0), 127) - y0c;
    int dxs = min(max(x0 + 1, 0), 127) - x0c;
    mWp[t * 2]     = __builtin_bit_cast(u32, __floats2half2_rn(ay0 * ax0, ay0 * ax1));
    mWp[t * 2 + 1] = __builtin_bit_cast(u32, __floats2half2_rn(ay1 * ax0, ay1 * ax1));
    mPos[t] = (u32)(((b << 14) + y0c * 128 + x0c) * 128) | (u32)dxs | ((u32)dys << 1);
  }
  __syncthreads();

  // ---- phase 1: sampling — lane = (pix 0..7)*8 + oct; bf16 gathers, f32 interp ----
  int oct16 = (lane & 7) << 4;         // byte offset of octet within pixel's 128B
  int oct8 = (lane & 7) << 3;          // u16 offset of octet within pixel's 64ch
  int p = wid * 8 + (lane >> 3);
  const char* xb = (const char*)xt;

#pragma unroll
  for (int k = 0; k < 9; ++k) {
    int t = p * 9 + k;
    u32 wlo = mWp[t * 2], whi = mWp[t * 2 + 1];
    u32 pm = mPos[t];
    u32 dxB = (pm & 1u) << 7;          // 128 B x-step
    u32 dyB = (pm & 2u) << 13;         // 16384 B y-step
    const char* pb = xb + (pm & 0xFFFFFF80u) + oct16;
    u32x4 c00 = *(const u32x4*)pb;
    u32x4 c01 = *(const u32x4*)(pb + dxB);
    u32x4 c10 = *(const u32x4*)(pb + dyB);
    u32x4 c11 = *(const u32x4*)(pb + dyB + dxB);
    __half2 hl = __builtin_bit_cast(__half2, wlo);
    __half2 hh = __builtin_bit_cast(__half2, whi);
    float w00 = __low2float(hl), w01 = __high2float(hl);
    float w10 = __low2float(hh), w11 = __high2float(hh);
    u32x4 out;
#pragma unroll
    for (int j = 0; j < 4; ++j) {
      float sL = fmaf(w11, bflo(c11[j]), fmaf(w10, bflo(c10[j]),
                 fmaf(w01, bflo(c01[j]), w00 * bflo(c00[j]))));
      float sH = fmaf(w11, bfhi(c11[j]), fmaf(w10, bfhi(c10[j]),
                 fmaf(w01, bfhi(c01[j]), w00 * bfhi(c00[j]))));
      out[j] = pkbf(sL, sH);
    }
    int idx = (p * 576 + k * 64 + oct8) ^ ((p & 7) << 3);
    *(u32x4*)&S[idx] = out;
  }

  s16x8 afr[18];
  const u16* wrow = Wb + (wid * 16 + (lane & 15)) * 576 + (lane >> 4) * 8;
#pragma unroll
  for (int kc = 0; kc < 18; ++kc)
    afr[kc] = *(const s16x8*)(wrow + kc * 32);

  __syncthreads();

  f32x4 zero = {0.f, 0.f, 0.f, 0.f};
  f32x4 acc[2] = {zero, zero};
#pragma unroll
  for (int kc = 0; kc < 18; ++kc) {
#pragma unroll
    for (int nf = 0; nf < 2; ++nf) {
      int row = nf * 16 + (lane & 15);
      int idx = (row * 576 + kc * 32 + (lane >> 4) * 8) ^ ((row & 7) << 3);
      bf16x8 bfr = __builtin_bit_cast(bf16x8, *(const s16x8*)&S[idx]);
      acc[nf] = __builtin_amdgcn_mfma_f32_16x16x32_bf16(
          __builtin_bit_cast(bf16x8, afr[kc]), bfr, acc[nf], 0, 0, 0);
    }
  }

  int obase = wid * 16 + (lane >> 4) * 4;
#pragma unroll
  for (int nf = 0; nf < 2; ++nf) {
    int pix = base + nf * 16 + (lane & 15);
    int hw = pix & 16383;
    float* yp = y + (size_t)b * (64 * HWSZ) + hw;
#pragma unroll
    for (int r = 0; r < 4; ++r) {
      int o = obase + r;
      yp[(size_t)o * HWSZ] = acc[nf][r] + db[o];
    }
  }
}

// ---- BN stats pass 1: one block per (batch, channel) plane, no atomics ----
__global__ void kstats(const float* __restrict__ y, float* __restrict__ part) {
  __shared__ float r1[256], r2[256];
  int bo = blockIdx.x;
  int tid = threadIdx.x;
  const float* yp = y + (size_t)bo * HWSZ;
  float s1 = 0.f, s2 = 0.f;
  for (int i = tid * 4; i < HWSZ; i += 1024) {
    f32x4 v = *(const f32x4*)(yp + i);
#pragma unroll
    for (int j = 0; j < 4; ++j) { s1 += v[j]; s2 += v[j] * v[j]; }
  }
  r1[tid] = s1; r2[tid] = s2;
  __syncthreads();
  for (int s = 128; s > 0; s >>= 1) {
    if (tid < s) { r1[tid] += r1[tid + s]; r2[tid] += r2[tid + s]; }
    __syncthreads();
  }
  if (tid == 0) { part[bo] = r1[0]; part[512 + bo] = r2[0]; }
}

// ---- BN finalize ----
__global__ void kbnf(const float* __restrict__ part, const float* __restrict__ gamma,
                     const float* __restrict__ beta, float* __restrict__ stats) {
  int o = threadIdx.x;
  if (o < 64) {
    float s1 = 0.f, s2 = 0.f;
#pragma unroll
    for (int b = 0; b < 8; ++b) {
      s1 += part[b * 64 + o];
      s2 += part[512 + b * 64 + o];
    }
    float m = s1 * (1.f / 131072.f);
    float v = s2 * (1.f / 131072.f) - m * m;
    float sc = gamma[o] * rsqrtf(v + 1e-5f);
    stats[128 + o] = sc;
    stats[192 + o] = beta[o] - m * sc;
  }
}

// ---- in-place scale/shift + PReLU on y (= d_out) ----
__global__ void kfinal(float* __restrict__ y, const float* __restrict__ stats,
                       const float* __restrict__ pa) {
  float a = pa[0];
  int total = NPIX * 64 / 4;
  for (int i = blockIdx.x * blockDim.x + threadIdx.x; i < total;
       i += gridDim.x * blockDim.x) {
    int o = (i >> 12) & 63;
    f32x4 v = ((const f32x4*)y)[i];
    float sc = stats[128 + o], sh = stats[192 + o];
#pragma unroll
    for (int j = 0; j < 4; ++j) {
      float t = fmaf(v[j], sc, sh);
      v[j] = t >= 0.f ? t : a * t;
    }
    ((f32x4*)y)[i] = v;
  }
}

extern "C" void kernel_launch(void* const* d_in, const int* in_sizes, int n_in,
                              void* d_out, int out_size, void* d_ws, size_t ws_size,
                              hipStream_t stream) {
  const float* x  = (const float*)d_in[0];
  const float* ow = (const float*)d_in[1];
  const float* ob = (const float*)d_in[2];
  const float* dw = (const float*)d_in[3];
  const float* db = (const float*)d_in[4];
  const float* gm = (const float*)d_in[5];
  const float* bt = (const float*)d_in[6];
  const float* pa = (const float*)d_in[7];
  char* ws = (char*)d_ws;
  u16*   xt    = (u16*)(ws + XT_OFF);
  float* offs  = (float*)(ws + OFFS_OFF);
  u16*   Wb    = (u16*)(ws + WB_OFF);
  u16*   Wo    = (u16*)(ws + WO_OFF);
  float* stats = (float*)(ws + STATS_OFF);
  float* part  = (float*)(ws + PART_OFF);
  float* y = (float*)d_out;   // d_out doubles as the pre-BN activation buffer

  kprep<<<216, 256, 0, stream>>>(dw, ow, Wb, Wo);
  ktrans<<<2048, 256, 0, stream>>>(x, xt);
  koffg<<<4096, 256, 0, stream>>>(xt, Wo, ob, offs);
  kdeform<<<4096, 256, 0, stream>>>(xt, offs, Wb, db, y);
  kstats<<<512, 256, 0, stream>>>(y, part);
  kbnf<<<1, 64, 0, stream>>>(part, gm, bt, stats);
  kfinal<<<2048, 256, 0, stream>>>(y, stats, pa);
}

// Round 13
// 134.809 us; speedup vs baseline: 2.3424x; 1.0404x over previous
//
#include <hip/hip_runtime.h>
#include <hip/hip_bf16.h>
#include <hip/hip_fp16.h>

typedef float f32x4 __attribute__((ext_vector_type(4)));
typedef float f32x2 __attribute__((ext_vector_type(2)));
typedef unsigned int u32;
typedef u32 u32x4 __attribute__((ext_vector_type(4)));
typedef __bf16 bf16x8 __attribute__((ext_vector_type(8)));
typedef short s16x8 __attribute__((ext_vector_type(8)));
typedef unsigned short u16;

#define HWSZ 16384
#define NPIX 131072

// ws byte offsets
#define XT_OFF    0u          // u16(bf16)[NPIX*64]  x transposed to NHWC (16.78 MB)
#define PART_OFF  33554432u   // float[4096*128]  per-block BN partials (2 MB)
#define WB_OFF    42991616u   // u16(bf16)[64*576]  deform_w, [o][k2*64+c]
#define STATS_OFF 43106816u   // float[256]: (unused)[128], scale[64], shift[64]
#define WO_OFF    43107840u   // u16(bf16)[32*576]  offset_w padded, [oc][k2*64+c]

__device__ inline u32 pkbf(float lo, float hi) {
  u16 l = __builtin_bit_cast(u16, __float2bfloat16(lo));
  u16 h = __builtin_bit_cast(u16, __float2bfloat16(hi));
  return (u32)l | ((u32)h << 16);
}
__device__ inline float bflo(u32 u) { return __builtin_bit_cast(float, u << 16); }
__device__ inline float bfhi(u32 u) { return __builtin_bit_cast(float, u & 0xFFFF0000u); }

// ---- prep: reorder/convert weights to bf16 ----
__global__ void kprep(const float* __restrict__ dw, const float* __restrict__ ow,
                      u16* __restrict__ Wb, u16* __restrict__ Wo) {
  int t = blockIdx.x * 256 + threadIdx.x;
  if (t < 36864) {                      // deform_w (64,64,3,3) -> Wb[o][k2*64+c] bf16
    int o = t / 576, r = t % 576;
    int c = r / 9, k2 = r % 9;
    __hip_bfloat16 h = __float2bfloat16(dw[t]);
    Wb[o * 576 + k2 * 64 + c] = __builtin_bit_cast(u16, h);
  } else if (t < 55296) {               // offset_w (18,64,3,3) -> Wo[oc][k2*64+c], pad to 32
    int t2 = t - 36864;
    int oc = t2 / 576, r = t2 % 576;
    int c = r / 9, k2 = r % 9;
    float v = (oc < 18) ? ow[(oc * 64 + c) * 9 + k2] : 0.f;
    __hip_bfloat16 h = __float2bfloat16(v);
    Wo[oc * 576 + k2 * 64 + c] = __builtin_bit_cast(u16, h);
  }
}

// ---- NCHW f32 -> NHWC bf16 transpose of x ----
__global__ void ktrans(const float* __restrict__ x, u16* __restrict__ xt) {
  __shared__ float tile[64][65];
  int blk = blockIdx.x;
  int b = blk >> 8, hwT = (blk & 255) * 64;
  int tx = threadIdx.x & 63, ty = threadIdx.x >> 6;
  const float* xp = x + (size_t)b * 64 * HWSZ;
#pragma unroll
  for (int r = 0; r < 16; ++r) {
    int c = r * 4 + ty;
    tile[c][tx] = xp[c * HWSZ + hwT + tx];
  }
  __syncthreads();
  u16* xo = xt + ((size_t)b * HWSZ + hwT) * 64;
#pragma unroll
  for (int r = 0; r < 16; ++r) {
    int hwl = r * 4 + ty;
    __hip_bfloat16 h = __float2bfloat16(tile[tx][hwl]);
    xo[hwl * 64 + tx] = __builtin_bit_cast(u16, h);
  }
}

// ---- fused: offset-conv GEMM -> offs in LDS -> meta -> sampling -> deform GEMM ----
// block: 256 thr = 4 waves; tile = 32 pixels; LDS: S 36864 + meta 3456 = 40320 B
// OFFT (float[32][20]) aliases S[0..1279] — phase-separated by barriers.
__global__ __launch_bounds__(256, 4) void kmain(
    const u16* __restrict__ xt, const u16* __restrict__ Wo,
    const float* __restrict__ offb, const u16* __restrict__ Wb,
    const float* __restrict__ db, float* __restrict__ y,
    float* __restrict__ part) {
  __shared__ u16 S[32 * 576];          // bf16, XOR-swizzled: u16idx ^= (row&7)<<3
  __shared__ u32 mWp[288 * 2];         // per (pix,tap): f16x2 {w00,w01},{w10,w11}
  __shared__ u32 mPos[288];            // pixel_byte(×128) | dxs | dys<<1
  float* OFFT = (float*)S;             // [32][20] floats, aliases S head
  int tid = threadIdx.x;
  int lane = tid & 63, wid = tid >> 6;
  int bid = blockIdx.x;
  int batch = bid & 7, tilei = bid >> 3;
  int base = (batch << 14) + tilei * 32;
  int b = batch;
  int hw0 = base & 16383;
  int h0 = hw0 >> 7, w0 = hw0 & 127;   // 32-px tile lies within row h0

  int oct = lane & 7;
  int p = wid * 8 + (lane >> 3);       // this lane's pixel (0..31)
  const char* xb = (const char*)xt;

  // ---- A: im2col S-build (straight bf16 copy) ----
  {
    int px = w0 + p;
#pragma unroll
    for (int k2 = 0; k2 < 9; ++k2) {
      int ky = k2 / 3, kx = k2 % 3;
      int yy = h0 - 1 + ky, xx = px - 1 + kx;
      u32x4 out = {0u, 0u, 0u, 0u};
      if ((unsigned)yy < 128u && (unsigned)xx < 128u) {
        const char* pb = xb + (size_t)(((b << 14) + yy * 128 + xx) * 128) + (oct << 4);
        out = *(const u32x4*)pb;
      }
      int idx = (p * 576 + k2 * 64 + oct * 8) ^ ((p & 7) << 3);
      *(u32x4*)&S[idx] = out;
    }
  }
  int mr = wid >> 1, nr = wid & 1;
  s16x8 ofr[18];
  {
    const u16* wrow = Wo + (mr * 16 + (lane & 15)) * 576 + (lane >> 4) * 8;
#pragma unroll
    for (int kc = 0; kc < 18; ++kc) ofr[kc] = *(const s16x8*)(wrow + kc * 32);
  }
  __syncthreads();

  // ---- B: offset-conv MFMA (18 per wave) ----
  f32x4 acco = {0.f, 0.f, 0.f, 0.f};
#pragma unroll
  for (int kc = 0; kc < 18; ++kc) {
    int row = nr * 16 + (lane & 15);
    int idx = (row * 576 + kc * 32 + (lane >> 4) * 8) ^ ((row & 7) << 3);
    bf16x8 bfr = __builtin_bit_cast(bf16x8, *(const s16x8*)&S[idx]);
    acco = __builtin_amdgcn_mfma_f32_16x16x32_bf16(
        __builtin_bit_cast(bf16x8, ofr[kc]), bfr, acco, 0, 0, 0);
  }
  __syncthreads();

  // ---- C: offs -> OFFT (LDS, aliases dead S head) ----
  {
    int pixl = nr * 16 + (lane & 15);
    int ocb = mr * 16 + (lane >> 4) * 4;
#pragma unroll
    for (int r = 0; r < 4; ++r) {
      int oc = ocb + r;
      if (oc < 18) OFFT[pixl * 20 + oc] = acco[r] + offb[oc];
    }
  }
  __syncthreads();

  // ---- D: per-(pixel,tap) meta (288 tasks) ----
  for (int t = tid; t < 288; t += 256) {
    int tp = t / 9, k2 = t - tp * 9;
    int pix = base + tp;
    int hw = pix & 16383;
    int hh = hw >> 7, ww = hw & 127;
    float dy = OFFT[tp * 20 + 2 * k2];
    float dx = OFFT[tp * 20 + 2 * k2 + 1];
    float sy = (float)(hh - 1 + k2 / 3) + dy;
    float sx = (float)(ww - 1 + k2 % 3) + dx;
    float fy = floorf(sy), fx = floorf(sx);
    int y0 = (int)fy, x0 = (int)fx;
    float wy1 = sy - fy, wx1 = sx - fx;
    float ay0 = ((unsigned)y0 < 128u) ? 1.f - wy1 : 0.f;
    float ay1 = ((unsigned)(y0 + 1) < 128u) ? wy1 : 0.f;
    float ax0 = ((unsigned)x0 < 128u) ? 1.f - wx1 : 0.f;
    float ax1 = ((unsigned)(x0 + 1) < 128u) ? wx1 : 0.f;
    int y0c = min(max(y0, 0), 127), x0c = min(max(x0, 0), 127);
    int dys = min(max(y0 + 1, 0), 127) - y0c;
    int dxs = min(max(x0 + 1, 0), 127) - x0c;
    mWp[t * 2]     = __builtin_bit_cast(u32, __floats2half2_rn(ay0 * ax0, ay0 * ax1));
    mWp[t * 2 + 1] = __builtin_bit_cast(u32, __floats2half2_rn(ay1 * ax0, ay1 * ax1));
    mPos[t] = (u32)(((b << 14) + y0c * 128 + x0c) * 128) | (u32)dxs | ((u32)dys << 1);
  }
  __syncthreads();

  // ---- E: sampling — bf16 gathers, packed-f32 interp, S overwrite ----
  int oct16 = oct << 4;
  int oct8 = oct << 3;
#pragma unroll
  for (int k = 0; k < 9; ++k) {
    int t = p * 9 + k;
    u32 wlo = mWp[t * 2], whi = mWp[t * 2 + 1];
    u32 pm = mPos[t];
    u32 dxB = (pm & 1u) << 7;          // 128 B x-step
    u32 dyB = (pm & 2u) << 13;         // 16384 B y-step
    const char* pb = xb + (pm & 0xFFFFFF80u) + oct16;
    u32x4 c00 = *(const u32x4*)pb;
    u32x4 c01 = *(const u32x4*)(pb + dxB);
    u32x4 c10 = *(const u32x4*)(pb + dyB);
    u32x4 c11 = *(const u32x4*)(pb + dyB + dxB);
    __half2 hl = __builtin_bit_cast(__half2, wlo);
    __half2 hh2 = __builtin_bit_cast(__half2, whi);
    float f00 = __low2float(hl), f01 = __high2float(hl);
    float f10 = __low2float(hh2), f11 = __high2float(hh2);
    f32x2 w00 = {f00, f00}, w01 = {f01, f01}, w10 = {f10, f10}, w11 = {f11, f11};
    u32x4 out;
#pragma unroll
    for (int j = 0; j < 4; ++j) {
      f32x2 v00 = {bflo(c00[j]), bfhi(c00[j])};
      f32x2 v01 = {bflo(c01[j]), bfhi(c01[j])};
      f32x2 v10 = {bflo(c10[j]), bfhi(c10[j])};
      f32x2 v11 = {bflo(c11[j]), bfhi(c11[j])};
      f32x2 s = v00 * w00;
      s += v01 * w01;
      s += v10 * w10;
      s += v11 * w11;
      out[j] = pkbf(s.x, s.y);
    }
    int idx = (p * 576 + k * 64 + oct8) ^ ((p & 7) << 3);
    *(u32x4*)&S[idx] = out;
  }

  s16x8 afr[18];
  {
    const u16* wrow = Wb + (wid * 16 + (lane & 15)) * 576 + (lane >> 4) * 8;
#pragma unroll
    for (int kc = 0; kc < 18; ++kc) afr[kc] = *(const s16x8*)(wrow + kc * 32);
  }
  __syncthreads();

  // ---- F: deform MFMA (36 per wave) ----
  f32x4 zero = {0.f, 0.f, 0.f, 0.f};
  f32x4 acc[2] = {zero, zero};
#pragma unroll
  for (int kc = 0; kc < 18; ++kc) {
#pragma unroll
    for (int nf = 0; nf < 2; ++nf) {
      int row = nf * 16 + (lane & 15);
      int idx = (row * 576 + kc * 32 + (lane >> 4) * 8) ^ ((row & 7) << 3);
      bf16x8 bfr = __builtin_bit_cast(bf16x8, *(const s16x8*)&S[idx]);
      acc[nf] = __builtin_amdgcn_mfma_f32_16x16x32_bf16(
          __builtin_bit_cast(bf16x8, afr[kc]), bfr, acc[nf], 0, 0, 0);
    }
  }

  // ---- G: epilogue — y write + per-block BN partials (no atomics) ----
  int obase = wid * 16 + (lane >> 4) * 4;
  float s1[4] = {0, 0, 0, 0}, s2[4] = {0, 0, 0, 0};
#pragma unroll
  for (int nf = 0; nf < 2; ++nf) {
    int pix = base + nf * 16 + (lane & 15);
    int hw = pix & 16383;
    float* yp = y + (size_t)b * (64 * HWSZ) + hw;
#pragma unroll
    for (int r = 0; r < 4; ++r) {
      int o = obase + r;
      float v = acc[nf][r] + db[o];
      yp[(size_t)o * HWSZ] = v;
      s1[r] += v;
      s2[r] += v * v;
    }
  }
#pragma unroll
  for (int m = 1; m < 16; m <<= 1) {
#pragma unroll
    for (int r = 0; r < 4; ++r) {
      s1[r] += __shfl_xor(s1[r], m, 64);
      s2[r] += __shfl_xor(s2[r], m, 64);
    }
  }
  if ((lane & 15) == 0) {
    float* pp = part + (size_t)bid * 128;
#pragma unroll
    for (int r = 0; r < 4; ++r) {
      pp[obase + r] = s1[r];
      pp[64 + obase + r] = s2[r];
    }
  }
}

// ---- BN finalize: reduce 4096-block partials, one block per channel ----
__global__ void kbnf(const float* __restrict__ part, const float* __restrict__ gamma,
                     const float* __restrict__ beta, float* __restrict__ stats) {
  __shared__ float r1[256], r2[256];
  int o = blockIdx.x;
  int tid = threadIdx.x;
  float s1 = 0.f, s2 = 0.f;
  for (int i = tid; i < 4096; i += 256) {
    s1 += part[(size_t)i * 128 + o];
    s2 += part[(size_t)i * 128 + 64 + o];
  }
  r1[tid] = s1; r2[tid] = s2;
  __syncthreads();
  for (int s = 128; s > 0; s >>= 1) {
    if (tid < s) { r1[tid] += r1[tid + s]; r2[tid] += r2[tid + s]; }
    __syncthreads();
  }
  if (tid == 0) {
    float m = r1[0] * (1.f / 131072.f);
    float v = r2[0] * (1.f / 131072.f) - m * m;
    float sc = gamma[o] * rsqrtf(v + 1e-5f);
    stats[128 + o] = sc;
    stats[192 + o] = beta[o] - m * sc;
  }
}

// ---- in-place scale/shift + PReLU on y (= d_out) ----
__global__ void kfinal(float* __restrict__ y, const float* __restrict__ stats,
                       const float* __restrict__ pa) {
  float a = pa[0];
  int total = NPIX * 64 / 4;
  for (int i = blockIdx.x * blockDim.x + threadIdx.x; i < total;
       i += gridDim.x * blockDim.x) {
    int o = (i >> 12) & 63;
    f32x4 v = ((const f32x4*)y)[i];
    float sc = stats[128 + o], sh = stats[192 + o];
#pragma unroll
    for (int j = 0; j < 4; ++j) {
      float t = fmaf(v[j], sc, sh);
      v[j] = t >= 0.f ? t : a * t;
    }
    ((f32x4*)y)[i] = v;
  }
}

extern "C" void kernel_launch(void* const* d_in, const int* in_sizes, int n_in,
                              void* d_out, int out_size, void* d_ws, size_t ws_size,
                              hipStream_t stream) {
  const float* x  = (const float*)d_in[0];
  const float* ow = (const float*)d_in[1];
  const float* ob = (const float*)d_in[2];
  const float* dw = (const float*)d_in[3];
  const float* db = (const float*)d_in[4];
  const float* gm = (const float*)d_in[5];
  const float* bt = (const float*)d_in[6];
  const float* pa = (const float*)d_in[7];
  char* ws = (char*)d_ws;
  u16*   xt    = (u16*)(ws + XT_OFF);
  float* part  = (float*)(ws + PART_OFF);
  u16*   Wb    = (u16*)(ws + WB_OFF);
  u16*   Wo    = (u16*)(ws + WO_OFF);
  float* stats = (float*)(ws + STATS_OFF);
  float* y = (float*)d_out;   // d_out doubles as the pre-BN activation buffer

  kprep<<<216, 256, 0, stream>>>(dw, ow, Wb, Wo);
  ktrans<<<2048, 256, 0, stream>>>(x, xt);
  kmain<<<4096, 256, 0, stream>>>(xt, Wo, ob, Wb, db, y, part);
  kbnf<<<64, 256, 0, stream>>>(part, gm, bt, stats);
  kfinal<<<2048, 256, 0, stream>>>(y, stats, pa);
}

// Round 14
// 131.860 us; speedup vs baseline: 2.3948x; 1.0224x over previous
//
#include <hip/hip_runtime.h>
#include <hip/hip_bf16.h>
#include <hip/hip_fp16.h>

typedef float f32x4 __attribute__((ext_vector_type(4)));
typedef float f32x2 __attribute__((ext_vector_type(2)));
typedef unsigned int u32;
typedef u32 u32x4 __attribute__((ext_vector_type(4)));
typedef __bf16 bf16x8 __attribute__((ext_vector_type(8)));
typedef short s16x8 __attribute__((ext_vector_type(8)));
typedef unsigned short u16;

#define HWSZ 16384
#define NPIX 131072

// ws byte offsets
#define XT_OFF    0u          // u16(bf16)[NPIX*64]  x transposed to NHWC (16.78 MB)
#define PART_OFF  33554432u   // float[4096*128]  per-block BN partials (2 MB)
#define WB_OFF    42991616u   // u16(bf16)[64*576]  deform_w, [o][k2*64+c]
#define STATS_OFF 43106816u   // float[256]: (unused)[128], scale[64], shift[64]
#define WO_OFF    43107840u   // u16(bf16)[32*576]  offset_w padded, [oc][k2*64+c]

__device__ inline u32 pkbf(float lo, float hi) {
  u16 l = __builtin_bit_cast(u16, __float2bfloat16(lo));
  u16 h = __builtin_bit_cast(u16, __float2bfloat16(hi));
  return (u32)l | ((u32)h << 16);
}
__device__ inline float bflo(u32 u) { return __builtin_bit_cast(float, u << 16); }
__device__ inline float bfhi(u32 u) { return __builtin_bit_cast(float, u & 0xFFFF0000u); }

// ---- prep: reorder/convert weights to bf16 ----
__global__ void kprep(const float* __restrict__ dw, const float* __restrict__ ow,
                      u16* __restrict__ Wb, u16* __restrict__ Wo) {
  int t = blockIdx.x * 256 + threadIdx.x;
  if (t < 36864) {                      // deform_w (64,64,3,3) -> Wb[o][k2*64+c] bf16
    int o = t / 576, r = t % 576;
    int c = r / 9, k2 = r % 9;
    __hip_bfloat16 h = __float2bfloat16(dw[t]);
    Wb[o * 576 + k2 * 64 + c] = __builtin_bit_cast(u16, h);
  } else if (t < 55296) {               // offset_w (18,64,3,3) -> Wo[oc][k2*64+c], pad to 32
    int t2 = t - 36864;
    int oc = t2 / 576, r = t2 % 576;
    int c = r / 9, k2 = r % 9;
    float v = (oc < 18) ? ow[(oc * 64 + c) * 9 + k2] : 0.f;
    __hip_bfloat16 h = __float2bfloat16(v);
    Wo[oc * 576 + k2 * 64 + c] = __builtin_bit_cast(u16, h);
  }
}

// ---- NCHW f32 -> NHWC bf16 transpose of x (vectorized 16B stores) ----
__global__ void ktrans(const float* __restrict__ x, u16* __restrict__ xt) {
  __shared__ float tile[64][65];
  int blk = blockIdx.x;
  int b = blk >> 8, hwT = (blk & 255) * 64;
  int tid = threadIdx.x;
  int tx = tid & 63, ty = tid >> 6;
  const float* xp = x + (size_t)b * 64 * HWSZ;
#pragma unroll
  for (int r = 0; r < 16; ++r) {
    int c = r * 4 + ty;
    tile[c][tx] = xp[c * HWSZ + hwT + tx];
  }
  __syncthreads();
  u16* xo = xt + ((size_t)b * HWSZ + hwT) * 64;
  int o8 = (tid & 7) * 8;
#pragma unroll
  for (int r = 0; r < 2; ++r) {
    int hwl = r * 32 + (tid >> 3);
    u32x4 out;
#pragma unroll
    for (int j = 0; j < 4; ++j)
      out[j] = pkbf(tile[o8 + 2 * j][hwl], tile[o8 + 2 * j + 1][hwl]);
    *(u32x4*)&xo[(size_t)hwl * 64 + o8] = out;
  }
}

// ---- fused: offset-conv GEMM -> offs in LDS -> meta -> sampling -> deform GEMM ----
// block: 256 thr = 4 waves; tile = 32 pixels; LDS: S 36864 + meta 3456 = 40320 B
// OFFT (float[32][20]) aliases S[0..1279] — phase-separated by barriers.
__global__ __launch_bounds__(256, 4) void kmain(
    const u16* __restrict__ xt, const u16* __restrict__ Wo,
    const float* __restrict__ offb, const u16* __restrict__ Wb,
    const float* __restrict__ db, float* __restrict__ y,
    float* __restrict__ part) {
  __shared__ u16 S[32 * 576];          // bf16, XOR-swizzled: u16idx ^= (row&7)<<3
  __shared__ u32 mWp[288 * 2];         // per (pix,tap): f16x2 {w00,w01},{w10,w11}
  __shared__ u32 mPos[288];            // pixel_byte(×128) | dxs | dys<<1
  float* OFFT = (float*)S;             // [32][20] floats, aliases S head
  int tid = threadIdx.x;
  int lane = tid & 63, wid = tid >> 6;
  int bid = blockIdx.x;
  int batch = bid & 7, tilei = bid >> 3;
  int base = (batch << 14) + tilei * 32;
  int b = batch;
  int hw0 = base & 16383;
  int h0 = hw0 >> 7, w0 = hw0 & 127;   // 32-px tile lies within row h0

  int oct = lane & 7;
  int p = wid * 8 + (lane >> 3);       // this lane's pixel (0..31)
  const char* xb = (const char*)xt;

  // ---- A: im2col S-build — batched branchless loads ----
  {
    int px = w0 + p;
    u32x4 ga[9];
    u32 va[9];
#pragma unroll
    for (int k2 = 0; k2 < 9; ++k2) {
      int ky = k2 / 3, kx = k2 % 3;
      int yy = h0 - 1 + ky, xx = px - 1 + kx;
      bool v = ((unsigned)yy < 128u) && ((unsigned)xx < 128u);
      const char* pb =
          v ? xb + (size_t)(((b << 14) + yy * 128 + xx) * 128) + (oct << 4) : xb;
      ga[k2] = *(const u32x4*)pb;
      va[k2] = v ? 0xFFFFFFFFu : 0u;
    }
    __builtin_amdgcn_sched_barrier(0);
#pragma unroll
    for (int k2 = 0; k2 < 9; ++k2) {
      u32x4 out;
#pragma unroll
      for (int j = 0; j < 4; ++j) out[j] = ga[k2][j] & va[k2];
      int idx = (p * 576 + k2 * 64 + oct * 8) ^ ((p & 7) << 3);
      *(u32x4*)&S[idx] = out;
    }
  }
  int mr = wid >> 1, nr = wid & 1;
  s16x8 ofr[18];
  {
    const u16* wrow = Wo + (mr * 16 + (lane & 15)) * 576 + (lane >> 4) * 8;
#pragma unroll
    for (int kc = 0; kc < 18; ++kc) ofr[kc] = *(const s16x8*)(wrow + kc * 32);
  }
  __syncthreads();

  // ---- B: offset-conv MFMA (18 per wave) ----
  f32x4 acco = {0.f, 0.f, 0.f, 0.f};
#pragma unroll
  for (int kc = 0; kc < 18; ++kc) {
    int row = nr * 16 + (lane & 15);
    int idx = (row * 576 + kc * 32 + (lane >> 4) * 8) ^ ((row & 7) << 3);
    bf16x8 bfr = __builtin_bit_cast(bf16x8, *(const s16x8*)&S[idx]);
    acco = __builtin_amdgcn_mfma_f32_16x16x32_bf16(
        __builtin_bit_cast(bf16x8, ofr[kc]), bfr, acco, 0, 0, 0);
  }
  __syncthreads();

  // ---- C: offs -> OFFT (LDS, aliases dead S head) ----
  {
    int pixl = nr * 16 + (lane & 15);
    int ocb = mr * 16 + (lane >> 4) * 4;
#pragma unroll
    for (int r = 0; r < 4; ++r) {
      int oc = ocb + r;
      if (oc < 18) OFFT[pixl * 20 + oc] = acco[r] + offb[oc];
    }
  }
  __syncthreads();

  // ---- D: per-(pixel,tap) meta (288 tasks) ----
  for (int t = tid; t < 288; t += 256) {
    int tp = t / 9, k2 = t - tp * 9;
    int pix = base + tp;
    int hw = pix & 16383;
    int hh = hw >> 7, ww = hw & 127;
    float dy = OFFT[tp * 20 + 2 * k2];
    float dx = OFFT[tp * 20 + 2 * k2 + 1];
    float sy = (float)(hh - 1 + k2 / 3) + dy;
    float sx = (float)(ww - 1 + k2 % 3) + dx;
    float fy = floorf(sy), fx = floorf(sx);
    int y0 = (int)fy, x0 = (int)fx;
    float wy1 = sy - fy, wx1 = sx - fx;
    float ay0 = ((unsigned)y0 < 128u) ? 1.f - wy1 : 0.f;
    float ay1 = ((unsigned)(y0 + 1) < 128u) ? wy1 : 0.f;
    float ax0 = ((unsigned)x0 < 128u) ? 1.f - wx1 : 0.f;
    float ax1 = ((unsigned)(x0 + 1) < 128u) ? wx1 : 0.f;
    int y0c = min(max(y0, 0), 127), x0c = min(max(x0, 0), 127);
    int dys = min(max(y0 + 1, 0), 127) - y0c;
    int dxs = min(max(x0 + 1, 0), 127) - x0c;
    mWp[t * 2]     = __builtin_bit_cast(u32, __floats2half2_rn(ay0 * ax0, ay0 * ax1));
    mWp[t * 2 + 1] = __builtin_bit_cast(u32, __floats2half2_rn(ay1 * ax0, ay1 * ax1));
    mPos[t] = (u32)(((b << 14) + y0c * 128 + x0c) * 128) | (u32)dxs | ((u32)dys << 1);
  }
  __syncthreads();

  // ---- E: sampling — 3×3-tap batches: issue 12 gathers, pin, interp ----
  int oct16 = oct << 4;
  int oct8 = oct << 3;
#pragma unroll
  for (int kb = 0; kb < 3; ++kb) {
    u32 wloA[3], whiA[3];
    u32x4 g[3][4];
#pragma unroll
    for (int j3 = 0; j3 < 3; ++j3) {
      int t = p * 9 + kb * 3 + j3;
      wloA[j3] = mWp[t * 2];
      whiA[j3] = mWp[t * 2 + 1];
      u32 pm = mPos[t];
      u32 dxB = (pm & 1u) << 7;        // 128 B x-step
      u32 dyB = (pm & 2u) << 13;       // 16384 B y-step
      const char* pb = xb + (pm & 0xFFFFFF80u) + oct16;
      g[j3][0] = *(const u32x4*)pb;
      g[j3][1] = *(const u32x4*)(pb + dxB);
      g[j3][2] = *(const u32x4*)(pb + dyB);
      g[j3][3] = *(const u32x4*)(pb + dyB + dxB);
    }
    __builtin_amdgcn_sched_barrier(0);
#pragma unroll
    for (int j3 = 0; j3 < 3; ++j3) {
      int k = kb * 3 + j3;
      __half2 hl = __builtin_bit_cast(__half2, wloA[j3]);
      __half2 hh2 = __builtin_bit_cast(__half2, whiA[j3]);
      float w00 = __low2float(hl), w01 = __high2float(hl);
      float w10 = __low2float(hh2), w11 = __high2float(hh2);
      u32x4 out;
#pragma unroll
      for (int j = 0; j < 4; ++j) {
        float sL = fmaf(w11, bflo(g[j3][3][j]), fmaf(w10, bflo(g[j3][2][j]),
                   fmaf(w01, bflo(g[j3][1][j]), w00 * bflo(g[j3][0][j]))));
        float sH = fmaf(w11, bfhi(g[j3][3][j]), fmaf(w10, bfhi(g[j3][2][j]),
                   fmaf(w01, bfhi(g[j3][1][j]), w00 * bfhi(g[j3][0][j]))));
        out[j] = pkbf(sL, sH);
      }
      int idx = (p * 576 + k * 64 + oct8) ^ ((p & 7) << 3);
      *(u32x4*)&S[idx] = out;
    }
  }

  s16x8 afr[18];
  {
    const u16* wrow = Wb + (wid * 16 + (lane & 15)) * 576 + (lane >> 4) * 8;
#pragma unroll
    for (int kc = 0; kc < 18; ++kc) afr[kc] = *(const s16x8*)(wrow + kc * 32);
  }
  __syncthreads();

  // ---- F: deform MFMA (36 per wave) ----
  f32x4 zero = {0.f, 0.f, 0.f, 0.f};
  f32x4 acc[2] = {zero, zero};
#pragma unroll
  for (int kc = 0; kc < 18; ++kc) {
#pragma unroll
    for (int nf = 0; nf < 2; ++nf) {
      int row = nf * 16 + (lane & 15);
      int idx = (row * 576 + kc * 32 + (lane >> 4) * 8) ^ ((row & 7) << 3);
      bf16x8 bfr = __builtin_bit_cast(bf16x8, *(const s16x8*)&S[idx]);
      acc[nf] = __builtin_amdgcn_mfma_f32_16x16x32_bf16(
          __builtin_bit_cast(bf16x8, afr[kc]), bfr, acc[nf], 0, 0, 0);
    }
  }

  // ---- G: epilogue — y write + per-block BN partials (no atomics) ----
  int obase = wid * 16 + (lane >> 4) * 4;
  float s1[4] = {0, 0, 0, 0}, s2[4] = {0, 0, 0, 0};
#pragma unroll
  for (int nf = 0; nf < 2; ++nf) {
    int pix = base + nf * 16 + (lane & 15);
    int hw = pix & 16383;
    float* yp = y + (size_t)b * (64 * HWSZ) + hw;
#pragma unroll
    for (int r = 0; r < 4; ++r) {
      int o = obase + r;
      float v = acc[nf][r] + db[o];
      yp[(size_t)o * HWSZ] = v;
      s1[r] += v;
      s2[r] += v * v;
    }
  }
#pragma unroll
  for (int m = 1; m < 16; m <<= 1) {
#pragma unroll
    for (int r = 0; r < 4; ++r) {
      s1[r] += __shfl_xor(s1[r], m, 64);
      s2[r] += __shfl_xor(s2[r], m, 64);
    }
  }
  if ((lane & 15) == 0) {
    float* pp = part + (size_t)bid * 128;
#pragma unroll
    for (int r = 0; r < 4; ++r) {
      pp[obase + r] = s1[r];
      pp[64 + obase + r] = s2[r];
    }
  }
}

// ---- BN finalize: reduce 4096-block partials, one block per channel ----
__global__ void kbnf(const float* __restrict__ part, const float* __restrict__ gamma,
                     const float* __restrict__ beta, float* __restrict__ stats) {
  __shared__ float r1[256], r2[256];
  int o = blockIdx.x;
  int tid = threadIdx.x;
  float s1 = 0.f, s2 = 0.f;
  for (int i = tid; i < 4096; i += 256) {
    s1 += part[(size_t)i * 128 + o];
    s2 += part[(size_t)i * 128 + 64 + o];
  }
  r1[tid] = s1; r2[tid] = s2;
  __syncthreads();
  for (int s = 128; s > 0; s >>= 1) {
    if (tid < s) { r1[tid] += r1[tid + s]; r2[tid] += r2[tid + s]; }
    __syncthreads();
  }
  if (tid == 0) {
    float m = r1[0] * (1.f / 131072.f);
    float v = r2[0] * (1.f / 131072.f) - m * m;
    float sc = gamma[o] * rsqrtf(v + 1e-5f);
    stats[128 + o] = sc;
    stats[192 + o] = beta[o] - m * sc;
  }
}

// ---- in-place scale/shift + PReLU on y (= d_out) ----
__global__ void kfinal(float* __restrict__ y, const float* __restrict__ stats,
                       const float* __restrict__ pa) {
  float a = pa[0];
  int total = NPIX * 64 / 4;
  for (int i = blockIdx.x * blockDim.x + threadIdx.x; i < total;
       i += gridDim.x * blockDim.x) {
    int o = (i >> 12) & 63;
    f32x4 v = ((const f32x4*)y)[i];
    float sc = stats[128 + o], sh = stats[192 + o];
#pragma unroll
    for (int j = 0; j < 4; ++j) {
      float t = fmaf(v[j], sc, sh);
      v[j] = t >= 0.f ? t : a * t;
    }
    ((f32x4*)y)[i] = v;
  }
}

extern "C" void kernel_launch(void* const* d_in, const int* in_sizes, int n_in,
                              void* d_out, int out_size, void* d_ws, size_t ws_size,
                              hipStream_t stream) {
  const float* x  = (const float*)d_in[0];
  const float* ow = (const float*)d_in[1];
  const float* ob = (const float*)d_in[2];
  const float* dw = (const float*)d_in[3];
  const float* db = (const float*)d_in[4];
  const float* gm = (const float*)d_in[5];
  const float* bt = (const float*)d_in[6];
  const float* pa = (const float*)d_in[7];
  char* ws = (char*)d_ws;
  u16*   xt    = (u16*)(ws + XT_OFF);
  float* part  = (float*)(ws + PART_OFF);
  u16*   Wb    = (u16*)(ws + WB_OFF);
  u16*   Wo    = (u16*)(ws + WO_OFF);
  float* stats = (float*)(ws + STATS_OFF);
  float* y = (float*)d_out;   // d_out doubles as the pre-BN activation buffer

  kprep<<<216, 256, 0, stream>>>(dw, ow, Wb, Wo);
  ktrans<<<2048, 256, 0, stream>>>(x, xt);
  kmain<<<4096, 256, 0, stream>>>(xt, Wo, ob, Wb, db, y, part);
  kbnf<<<64, 256, 0, stream>>>(part, gm, bt, stats);
  kfinal<<<2048, 256, 0, stream>>>(y, stats, pa);
}